// Round 7
// baseline (519.937 us; speedup 1.0000x reference)
//
#include <hip/hip_runtime.h>
#include <hip/hip_bf16.h>

#define N_ 2
#define C_ 64
#define D_ 8
#define H_ 56
#define W_ 56
#define HW_ (H_*W_)        // 3136
#define P_ (D_*HW_)        // 25088
#define G_ 8
#define CPG_ 8
#define K_ 27
#define CO_OFF_ 648        // G * 3 * K
#define MP_ 768            // conv_off M padded (rows 648+ zero)
#define KK_ 1728           // GEMM K dim (= 27*64, k-major: ktap*64 + ci)
#define KB_ (KK_*2)        // bytes per bf16 row

typedef __attribute__((ext_vector_type(8))) short shortx8;
typedef __attribute__((ext_vector_type(4))) float floatx4;
#define AS1 __attribute__((address_space(1)))
#define AS3 __attribute__((address_space(3)))

__device__ inline float b2f(unsigned short u) {
    union { unsigned u; float f; } x; x.u = ((unsigned)u) << 16; return x.f;
}
__device__ inline unsigned short f2b(float f) {
    union { float f; unsigned u; } x; x.f = f;
    unsigned r = (x.u + 0x7fffu + ((x.u >> 16) & 1u)) >> 16;   // RNE
    return (unsigned short)r;
}
__device__ inline float lof(unsigned u) { union { unsigned u; float f; } x; x.u = u << 16; return x.f; }
__device__ inline float hif(unsigned u) { union { unsigned u; float f; } x; x.u = u & 0xffff0000u; return x.f; }
// HW packed f32->bf16 (RNE), 1 inst for 2 values.
__device__ inline unsigned cvt_pk_bf16(float a, float b) {
    unsigned r;
    asm("v_cvt_pk_bf16_f32 %0, %1, %2" : "=v"(r) : "v"(a), "v"(b));
    return r;
}

// off layout: off2[(g*27+kt)*P + p][3] bf16 (interleaved comps, 65 MB total)

// ---------------------------------------------------------------------------
// x [N][64][P] fp32 -> xt [N][P][64] bf16  (64p x 64c LDS tile transpose)
// ---------------------------------------------------------------------------
__global__ __launch_bounds__(256) void transpose_xt_kernel(
    const float* __restrict__ x, unsigned short* __restrict__ xt)
{
    __shared__ unsigned short tile[64][65];
    int b  = blockIdx.x;
    int n  = b / (P_/64);
    int p0 = (b % (P_/64))*64;
    int tid = threadIdx.x;
    int j  = tid & 63;
    int c0 = (tid >> 6)*16;
    for (int r = 0; r < 16; ++r)
        tile[c0 + r][j] = f2b(x[((size_t)n*C_ + c0 + r)*P_ + p0 + j]);
    __syncthreads();
    unsigned* dst = (unsigned*)(xt + ((size_t)n*P_ + p0)*C_);
    #pragma unroll
    for (int it = 0; it < 8; ++it) {
        int wi  = it*256 + tid;
        int row = wi >> 5;
        int c   = (wi & 31)*2;
        unsigned lo = tile[c][row], hi = tile[c+1][row];
        dst[(size_t)row*32 + (wi & 31)] = lo | (hi << 16);
    }
}

// w_off [648][64][27] fp32 -> A1k [768][kk*64+ci] bf16 (k-major, zero-pad rows)
__global__ __launch_bounds__(256) void permA1k_kernel(
    const float* __restrict__ w, unsigned short* __restrict__ A)
{
    int i = blockIdx.x*256 + threadIdx.x;
    if (i >= MP_*KK_) return;
    int m = i / KK_, r = i % KK_;
    int kk = r / 64, ci = r % 64;
    A[i] = (m < CO_OFF_) ? f2b(w[((size_t)m*C_ + ci)*K_ + kk]) : (unsigned short)0;
}

// w [O=64][I=64][27] fp32 -> At[o][k*64+i] bf16 (k-major)
__global__ __launch_bounds__(256) void perm_w_kernel(
    const float* __restrict__ w, unsigned short* __restrict__ At)
{
    int tid = blockIdx.x*256 + threadIdx.x;
    if (tid >= C_*KK_) return;
    int o  = tid / KK_;
    int r  = tid % KK_;
    int k  = r / 64, i = r % 64;
    At[tid] = f2b(w[((size_t)o*C_ + i)*K_ + k]);
}

// ---------------------------------------------------------------------------
// conv_off fused main v2: 128m x 256p tile. m-tiles 0..4 (rows 0..639).
// ---------------------------------------------------------------------------
__global__ __launch_bounds__(256, 2) void conv_off_fused(
    const unsigned short* __restrict__ A,    // A1k [768][1728]
    const unsigned short* __restrict__ xt,   // [N][P][64] bf16
    const float* __restrict__ bias,          // [648]
    unsigned short* __restrict__ off2)       // [N][216*P][3] bf16
{
    __shared__ __align__(16) short As[2][16*512];   // 32 KB (128m x 64k dbuf)
    __shared__ __align__(16) short Bs[32*512];      // 32 KB (256p x 64c)
    int tid = threadIdx.x;
    int w = tid >> 6, lane = tid & 63;
    int n   = blockIdx.x / 490;
    int bid = blockIdx.x % 490;
    int mt = bid / 98, nt = bid % 98;    // consecutive blocks share mt (A L2 reuse)
    int m0 = mt*128, p0 = nt*256;
    int lm = lane & 15, lq = lane >> 4;

    const unsigned short* xtn = xt + (size_t)n*P_*C_;
    unsigned short* out2 = off2 + (size_t)n*216*P_*3;

    const char* Ab0 = (const char*)A + (size_t)(m0 + w*32 + lm)*KB_ + lq*16;
    const char* Ab1 = Ab0 + (size_t)16*KB_;

    int oct = lane & 7;
    int prj[8], dj[8], hj[8], wj[8];
    #pragma unroll
    for (int j = 0; j < 8; ++j) {
        int prow = j*32 + w*8 + (lane >> 3);
        prj[j] = prow;
        int p = p0 + prow;
        dj[j] = p / HW_;
        int hw2 = p % HW_;
        hj[j] = hw2 / W_;
        wj[j] = hw2 % W_;
    }

    auto stageA = [&](int kt, int buf) {
        __builtin_amdgcn_global_load_lds((const AS1 unsigned*)(Ab0 + kt*128),      (AS3 unsigned*)(&As[buf][(w*2)*512]),     16, 0, 0);
        __builtin_amdgcn_global_load_lds((const AS1 unsigned*)(Ab1 + kt*128),      (AS3 unsigned*)(&As[buf][(w*2+1)*512]),   16, 0, 0);
        __builtin_amdgcn_global_load_lds((const AS1 unsigned*)(Ab0 + kt*128 + 64), (AS3 unsigned*)(&As[buf][(8+w*2)*512]),   16, 0, 0);
        __builtin_amdgcn_global_load_lds((const AS1 unsigned*)(Ab1 + kt*128 + 64), (AS3 unsigned*)(&As[buf][(8+w*2+1)*512]), 16, 0, 0);
    };
    auto loadB = [&](int kt, uint4* B) {
        int kd = kt/9 - 1, kh = (kt/3)%3 - 1, kw = kt%3 - 1;
        int delta = kd*HW_ + kh*W_ + kw;
        #pragma unroll
        for (int j = 0; j < 8; ++j) {
            bool v = ((unsigned)(dj[j]+kd) < (unsigned)D_) &&
                     ((unsigned)(hj[j]+kh) < (unsigned)H_) &&
                     ((unsigned)(wj[j]+kw) < (unsigned)W_);
            uint4 val = {0u,0u,0u,0u};
            if (v) val = *(const uint4*)(xtn + (size_t)(p0 + prj[j] + delta)*C_ + oct*8);
            B[j] = val;
        }
    };

    int mh = w >> 1, nh = w & 1;
    floatx4 acc[4][8];
    #pragma unroll
    for (int i = 0; i < 4; ++i)
        #pragma unroll
        for (int j = 0; j < 8; ++j)
            acc[i][j] = (floatx4){0.f, 0.f, 0.f, 0.f};

    uint4 Bcur[8], Bnext[8];
    #pragma unroll
    for (int j = 0; j < 8; ++j) Bnext[j] = (uint4){0u,0u,0u,0u};
    stageA(0, 0);
    loadB(0, Bcur);

    for (int kt = 0; kt < 27; ++kt) {
        int buf = kt & 1;
        __syncthreads();
        #pragma unroll
        for (int j = 0; j < 8; ++j) {
            int chunk = (oct>>2)*16 + (prj[j]>>4);
            *(uint4*)&Bs[chunk*512 + ((oct&3)*16 + ((prj[j]&15) ^ oct))*8] = Bcur[j];
        }
        __syncthreads();
        if (kt < 26) { stageA(kt+1, buf^1); loadB(kt+1, Bnext); }
        #pragma unroll
        for (int ks = 0; ks < 2; ++ks) {
            int swzB = (lq*16 + (lm ^ (ks*4 + lq)))*8;
            shortx8 a[4];
            #pragma unroll
            for (int i = 0; i < 4; ++i) a[i] = *(const shortx8*)&As[buf][(ks*8 + 4*mh + i)*512 + lane*8];
            #pragma unroll
            for (int j = 0; j < 8; ++j) {
                shortx8 b = *(const shortx8*)&Bs[(ks*16 + 8*nh + j)*512 + swzB];
                #pragma unroll
                for (int i = 0; i < 4; ++i)
                    acc[i][j] = __builtin_amdgcn_mfma_f32_16x16x32_bf16(a[i], b, acc[i][j], 0, 0, 0);
            }
        }
        #pragma unroll
        for (int j = 0; j < 8; ++j) Bcur[j] = Bnext[j];
    }

    #pragma unroll
    for (int i = 0; i < 4; ++i) {
        int cob = m0 + (4*mh+i)*16 + lq*4;
        #pragma unroll
        for (int r = 0; r < 4; ++r) {
            int co = cob + r;    // < 640 always (mt <= 4)
            float bv = bias[co];
            int row2 = co / 3, comp = co % 3;
            size_t base = (size_t)row2*P_*3 + comp;
            #pragma unroll
            for (int j = 0; j < 8; ++j) {
                int col = p0 + (8*nh+j)*16 + lm;
                out2[base + (size_t)col*3] = f2b(acc[i][j][r] + bv);
            }
        }
    }
}

// ---------------------------------------------------------------------------
// conv_off tail: rows 640..655 (648..655 zero-padded). 16x128 tile.
// ---------------------------------------------------------------------------
__global__ __launch_bounds__(256) void conv_off_tail(
    const unsigned short* __restrict__ A,    // A1k [768][1728]
    const unsigned short* __restrict__ xt,   // [N][P][64] bf16
    const float* __restrict__ bias,          // [648]
    unsigned short* __restrict__ off2)       // [N][216*P][3] bf16
{
    __shared__ __align__(16) short As[54*512];
    __shared__ __align__(16) short Bs[16*512];
    int tid = threadIdx.x;
    int w = tid >> 6, lane = tid & 63;
    int n  = blockIdx.x / 196;
    int p0 = (blockIdx.x % 196)*128;
    int lm = lane & 15, lq = lane >> 4;

    const unsigned short* xtn = xt + (size_t)n*P_*C_;
    unsigned short* out2 = off2 + (size_t)n*216*P_*3;

    const char* Abase = (const char*)A + (size_t)(640 + lm)*KB_ + lq*16;
    for (int ch = w; ch < 54; ch += 4)
        __builtin_amdgcn_global_load_lds((const AS1 unsigned*)(Abase + ch*64),
                                         (AS3 unsigned*)(As + ch*512), 16, 0, 0);

    int oct = lane & 7;
    int prj[4], dj[4], hj[4], wj[4];
    #pragma unroll
    for (int j = 0; j < 4; ++j) {
        int prow = j*32 + w*8 + (lane >> 3);
        prj[j] = prow;
        int p = p0 + prow;
        dj[j] = p / HW_;
        int hw2 = p % HW_;
        hj[j] = hw2 / W_;
        wj[j] = hw2 % W_;
    }
    auto loadB = [&](int kt, uint4* B) {
        int kd = kt/9 - 1, kh = (kt/3)%3 - 1, kw = kt%3 - 1;
        int delta = kd*HW_ + kh*W_ + kw;
        #pragma unroll
        for (int j = 0; j < 4; ++j) {
            bool v = ((unsigned)(dj[j]+kd) < (unsigned)D_) &&
                     ((unsigned)(hj[j]+kh) < (unsigned)H_) &&
                     ((unsigned)(wj[j]+kw) < (unsigned)W_);
            uint4 val = {0u,0u,0u,0u};
            if (v) val = *(const uint4*)(xtn + (size_t)(p0 + prj[j] + delta)*C_ + oct*8);
            B[j] = val;
        }
    };

    floatx4 acc[2];
    acc[0] = (floatx4){0.f,0.f,0.f,0.f};
    acc[1] = (floatx4){0.f,0.f,0.f,0.f};

    uint4 Bcur[4], Bnext[4];
    #pragma unroll
    for (int j = 0; j < 4; ++j) Bnext[j] = (uint4){0u,0u,0u,0u};
    loadB(0, Bcur);

    for (int kt = 0; kt < 27; ++kt) {
        __syncthreads();
        #pragma unroll
        for (int j = 0; j < 4; ++j) {
            int chunk = (oct>>2)*8 + (prj[j]>>4);
            *(uint4*)&Bs[chunk*512 + ((oct&3)*16 + ((prj[j]&15) ^ oct))*8] = Bcur[j];
        }
        __syncthreads();
        if (kt < 26) loadB(kt+1, Bnext);
        #pragma unroll
        for (int ks = 0; ks < 2; ++ks) {
            int swzB = (lq*16 + (lm ^ (ks*4 + lq)))*8;
            shortx8 a = *(const shortx8*)&As[(kt*2 + ks)*512 + lane*8];
            #pragma unroll
            for (int j = 0; j < 2; ++j) {
                shortx8 b = *(const shortx8*)&Bs[(ks*8 + w*2 + j)*512 + swzB];
                acc[j] = __builtin_amdgcn_mfma_f32_16x16x32_bf16(a, b, acc[j], 0, 0, 0);
            }
        }
        #pragma unroll
        for (int j = 0; j < 4; ++j) Bcur[j] = Bnext[j];
    }

    #pragma unroll
    for (int j = 0; j < 2; ++j) {
        #pragma unroll
        for (int r = 0; r < 4; ++r) {
            int co = 640 + lq*4 + r;
            if (co < CO_OFF_) {
                int col = p0 + w*32 + j*16 + lm;
                out2[((size_t)(co/3)*P_ + col)*3 + (co%3)] = f2b(acc[j][r] + bias[co]);
            }
        }
    }
}

// ---------------------------------------------------------------------------
// deform fused (R6 known-good, ~172 us): N=32 tiles, A dbuf + B dbuf in LDS
// -> ONE barrier per kt; gather pipeline inside the tap.
// ---------------------------------------------------------------------------
__global__ __launch_bounds__(256) void deform_fused(
    const unsigned short* __restrict__ xt,   // [N][P][64] bf16
    const unsigned short* __restrict__ off2, // [N][216*P][3] bf16
    const unsigned short* __restrict__ A,    // A1t [64][1728]
    unsigned short* __restrict__ y1t)        // [N][P][64] bf16
{
    __shared__ __align__(16) short SH[12288]; // A dbuf 2x4096, B dbuf 2x2048
    int tid = threadIdx.x;
    int w = tid >> 6, lane = tid & 63;
    int n  = blockIdx.x / (P_/32);
    int p0 = (blockIdx.x % (P_/32))*32;
    int lm = lane & 15, lq = lane >> 4;

    const unsigned short* offn = off2 + (size_t)n*216*P_*3;
    const uint4* xg0 = (const uint4*)(xt + (size_t)n*P_*C_);

    const char* Ab = (const char*)A + (size_t)(w*16 + lm)*KB_ + lq*16;

    int g = lane & 7;
    int prow = tid >> 3;          // 0..31
    int p = p0 + prow;
    int dd = p / HW_;
    int hw2 = p % HW_;
    int hh = hw2 / W_;
    int ww = hw2 % W_;
    int bchunk = (g>>2)*2 + (prow>>4);
    int boffs  = ((g&3)*16 + ((prow&15) ^ g))*8;

    auto stageA = [&](int kt, int buf) {
        __builtin_amdgcn_global_load_lds((const AS1 unsigned*)(Ab + kt*128),      (AS3 unsigned*)(SH + buf*4096 + w*512),     16, 0, 0);
        __builtin_amdgcn_global_load_lds((const AS1 unsigned*)(Ab + kt*128 + 64), (AS3 unsigned*)(SH + buf*4096 + (4+w)*512), 16, 0, 0);
    };
    auto loadOff = [&](int kt, float* o) {
        size_t idx = ((size_t)(g*K_ + kt)*P_ + p)*3;
        o[0] = b2f(offn[idx]);
        o[1] = b2f(offn[idx + 1]);
        o[2] = b2f(offn[idx + 2]);
    };
    auto issueCorners = [&](int kt, float* o, uint4* V, float* Wt) {
        int kd = kt/9 - 1, kh = (kt/3)%3 - 1, kw = kt%3 - 1;
        float pd = (float)(dd + kd) + o[0];
        float ph = (float)(hh + kh) + o[1];
        float pw = (float)(ww + kw) + o[2];
        float fd0 = floorf(pd), fh0 = floorf(ph), fw0 = floorf(pw);
        int d0 = (int)fd0, h0 = (int)fh0, w0i = (int)fw0;
        float fd = pd - fd0, fh = ph - fh0, fw = pw - fw0;
        int dc0 = min(max(d0, 0), D_-1),   dc1 = min(max(d0+1, 0), D_-1);
        int hc0 = min(max(h0, 0), H_-1),   hc1 = min(max(h0+1, 0), H_-1);
        int wc0 = min(max(w0i, 0), W_-1),  wc1 = min(max(w0i+1, 0), W_-1);
        float wd0 = ((unsigned)d0      < (unsigned)D_) ? 1.f - fd : 0.f;
        float wd1 = ((unsigned)(d0+1)  < (unsigned)D_) ? fd       : 0.f;
        float wh0 = ((unsigned)h0      < (unsigned)H_) ? 1.f - fh : 0.f;
        float wh1 = ((unsigned)(h0+1)  < (unsigned)H_) ? fh       : 0.f;
        float ww0 = ((unsigned)w0i     < (unsigned)W_) ? 1.f - fw : 0.f;
        float ww1 = ((unsigned)(w0i+1) < (unsigned)W_) ? fw       : 0.f;
        int rb00 = (dc0*H_ + hc0)*W_, rb01 = (dc0*H_ + hc1)*W_;
        int rb10 = (dc1*H_ + hc0)*W_, rb11 = (dc1*H_ + hc1)*W_;
        float wdh00 = wd0*wh0, wdh01 = wd0*wh1, wdh10 = wd1*wh0, wdh11 = wd1*wh1;
        V[0] = xg0[(size_t)(rb00+wc0)*8 + g];  Wt[0] = wdh00*ww0;
        V[1] = xg0[(size_t)(rb00+wc1)*8 + g];  Wt[1] = wdh00*ww1;
        V[2] = xg0[(size_t)(rb01+wc0)*8 + g];  Wt[2] = wdh01*ww0;
        V[3] = xg0[(size_t)(rb01+wc1)*8 + g];  Wt[3] = wdh01*ww1;
        V[4] = xg0[(size_t)(rb10+wc0)*8 + g];  Wt[4] = wdh10*ww0;
        V[5] = xg0[(size_t)(rb10+wc1)*8 + g];  Wt[5] = wdh10*ww1;
        V[6] = xg0[(size_t)(rb11+wc0)*8 + g];  Wt[6] = wdh11*ww0;
        V[7] = xg0[(size_t)(rb11+wc1)*8 + g];  Wt[7] = wdh11*ww1;
    };
    auto reduceCorners = [&](uint4* V, float* Wt, uint4& o4) {
        float res[CPG_];
        #pragma unroll
        for (int c = 0; c < CPG_; ++c) res[c] = 0.f;
        #pragma unroll
        for (int c = 0; c < 8; ++c) {
            uint4 v4 = V[c];
            float wgt = Wt[c];
            res[0] = fmaf(wgt, lof(v4.x), res[0]);
            res[1] = fmaf(wgt, hif(v4.x), res[1]);
            res[2] = fmaf(wgt, lof(v4.y), res[2]);
            res[3] = fmaf(wgt, hif(v4.y), res[3]);
            res[4] = fmaf(wgt, lof(v4.z), res[4]);
            res[5] = fmaf(wgt, hif(v4.z), res[5]);
            res[6] = fmaf(wgt, lof(v4.w), res[6]);
            res[7] = fmaf(wgt, hif(v4.w), res[7]);
        }
        o4.x = cvt_pk_bf16(res[0], res[1]);
        o4.y = cvt_pk_bf16(res[2], res[3]);
        o4.z = cvt_pk_bf16(res[4], res[5]);
        o4.w = cvt_pk_bf16(res[6], res[7]);
    };

    int mh = w >> 1, nh = w & 1;
    floatx4 acc[2];
    acc[0] = (floatx4){0.f,0.f,0.f,0.f};
    acc[1] = (floatx4){0.f,0.f,0.f,0.f};

    float offA[3], offB[3], offT[3];
    uint4 Vv[8]; float Wt[8];
    uint4 o4cur;

    stageA(0, 0);
    loadOff(0, offA);
    loadOff(1, offB);
    issueCorners(0, offA, Vv, Wt);
    reduceCorners(Vv, Wt, o4cur);
    *(uint4*)&SH[8192 + bchunk*512 + boffs] = o4cur;   // B(0) -> Bs buf 0

    for (int kt = 0; kt < 27; ++kt) {
        int buf = kt & 1;
        __syncthreads();   // Bs[buf] writes + As[buf] staging drained
        if (kt < 26) {
            stageA(kt+1, buf^1);
            if (kt < 25) loadOff(kt+2, offT);
            issueCorners(kt+1, offB, Vv, Wt);
        }
        #pragma unroll
        for (int ks = 0; ks < 2; ++ks) {
            int swzB = (lq*16 + (lm ^ (ks*4 + lq)))*8;
            shortx8 b = *(const shortx8*)&SH[8192 + buf*2048 + (ks*2 + nh)*512 + swzB];
            #pragma unroll
            for (int i = 0; i < 2; ++i) {
                shortx8 a = *(const shortx8*)&SH[buf*4096 + (ks*4 + 2*mh+i)*512 + lane*8];
                acc[i] = __builtin_amdgcn_mfma_f32_16x16x32_bf16(a, b, acc[i], 0, 0, 0);
            }
        }
        if (kt < 26) {
            reduceCorners(Vv, Wt, o4cur);
            *(uint4*)&SH[8192 + (buf^1)*2048 + bchunk*512 + boffs] = o4cur;
            offB[0] = offT[0]; offB[1] = offT[1]; offB[2] = offT[2];
        }
    }

    // epilogue: transpose 64o x 32p tile to y1t[p][o] via LDS (stride 72)
    __syncthreads();
    #pragma unroll
    for (int i = 0; i < 2; ++i) {
        int ob = mh*32 + i*16 + lq*4;
        int pc = nh*16 + lm;
        #pragma unroll
        for (int rr = 0; rr < 4; ++rr)
            SH[pc*72 + ob + rr] = (short)f2b(acc[i][rr]);
    }
    __syncthreads();
    {
        int row = tid >> 3, seg = tid & 7;
        uint4 v = *(const uint4*)&SH[row*72 + seg*8];
        *(uint4*)(y1t + ((size_t)n*P_ + p0 + row)*C_ + seg*8) = v;
    }
}

// ---------------------------------------------------------------------------
// conv2 fused v3: As QUAD-buffer, barrier every 2 taps (27 -> 15 barriers).
// __syncthreads drains vmcnt(0), so load cover is capped at issue->barrier
// distance; doubling the group doubles that cover and halves drain count.
// B per-lane registers (2-slot VA/VB), cvt_pk pack.
// ---------------------------------------------------------------------------
__global__ __launch_bounds__(256) void conv2_fused(
    const unsigned short* __restrict__ y1t,  // [N][P][64] bf16
    const float* __restrict__ st1,           // [64] scale, [64] shift
    const unsigned short* __restrict__ A,    // A2t [64][1728]
    const float* __restrict__ bias,          // [64]
    unsigned short* __restrict__ y2)         // [N][64][P] bf16
{
    __shared__ __align__(16) short As[4][4096];   // 32 KB quad-buffer
    __shared__ float sc[64], sf[64];
    int tid = threadIdx.x;
    if (tid < 64) sc[tid] = st1[tid];
    else if (tid < 128) sf[tid-64] = st1[tid];
    int w = tid >> 6, lane = tid & 63;
    int n  = blockIdx.x / (P_/64);
    int p0 = (blockIdx.x % (P_/64))*64;
    int lm = lane & 15, lq = lane >> 4;

    const unsigned short* y1n = y1t + (size_t)n*P_*C_;
    unsigned short* y2n = y2 + (size_t)n*C_*P_;
    const char* Ab = (const char*)A + (size_t)(w*16 + lm)*KB_ + lq*16;

    int p = p0 + w*16 + lm;
    int dd = p / HW_, hw2 = p % HW_;
    int hh = hw2 / W_, ww = hw2 % W_;

    auto stageA = [&](int kt) {
        int buf = kt & 3;
        __builtin_amdgcn_global_load_lds((const AS1 unsigned*)(Ab + kt*128),      (AS3 unsigned*)(&As[buf][w*512]),     16, 0, 0);
        __builtin_amdgcn_global_load_lds((const AS1 unsigned*)(Ab + kt*128 + 64), (AS3 unsigned*)(&As[buf][(4+w)*512]), 16, 0, 0);
    };
    auto issueV = [&](int kt, uint4* V, int& M) {
        int kd = kt/9 - 1, kh = (kt/3)%3 - 1, kw = kt%3 - 1;
        int delta = kd*HW_ + kh*W_ + kw;
        bool v = ((unsigned)(dd+kd) < (unsigned)D_) &&
                 ((unsigned)(hh+kh) < (unsigned)H_) &&
                 ((unsigned)(ww+kw) < (unsigned)W_);
        M = v ? 1 : 0;
        #pragma unroll
        for (int ks = 0; ks < 2; ++ks) {
            uint4 val = {0u,0u,0u,0u};
            if (v) val = *(const uint4*)(y1n + (size_t)(p + delta)*C_ + (ks*4 + lq)*8);
            V[ks] = val;
        }
    };
    auto reduceT = [&](uint4 V, int ks, int M) -> shortx8 {
        uint4 o4 = {0u,0u,0u,0u};
        if (M) {
            int cb = (ks*4 + lq)*8;
            float r0 = fmaxf(lof(V.x)*sc[cb+0] + sf[cb+0], 0.f);
            float r1 = fmaxf(hif(V.x)*sc[cb+1] + sf[cb+1], 0.f);
            float r2 = fmaxf(lof(V.y)*sc[cb+2] + sf[cb+2], 0.f);
            float r3 = fmaxf(hif(V.y)*sc[cb+3] + sf[cb+3], 0.f);
            float r4 = fmaxf(lof(V.z)*sc[cb+4] + sf[cb+4], 0.f);
            float r5 = fmaxf(hif(V.z)*sc[cb+5] + sf[cb+5], 0.f);
            float r6 = fmaxf(lof(V.w)*sc[cb+6] + sf[cb+6], 0.f);
            float r7 = fmaxf(hif(V.w)*sc[cb+7] + sf[cb+7], 0.f);
            o4.x = cvt_pk_bf16(r0, r1);
            o4.y = cvt_pk_bf16(r2, r3);
            o4.z = cvt_pk_bf16(r4, r5);
            o4.w = cvt_pk_bf16(r6, r7);
        }
        return *(shortx8*)&o4;
    };

    floatx4 acc[4];
    #pragma unroll
    for (int i = 0; i < 4; ++i) acc[i] = (floatx4){0.f,0.f,0.f,0.f};

    auto mfmaTap = [&](int kt, shortx8 b0, shortx8 b1) {
        int buf = kt & 3;
        #pragma unroll
        for (int i = 0; i < 4; ++i) {
            shortx8 a = *(const shortx8*)&As[buf][(0*4 + i)*512 + lane*8];
            acc[i] = __builtin_amdgcn_mfma_f32_16x16x32_bf16(a, b0, acc[i], 0, 0, 0);
        }
        #pragma unroll
        for (int i = 0; i < 4; ++i) {
            shortx8 a = *(const shortx8*)&As[buf][(1*4 + i)*512 + lane*8];
            acc[i] = __builtin_amdgcn_mfma_f32_16x16x32_bf16(a, b1, acc[i], 0, 0, 0);
        }
    };

    uint4 VA[2], VB[2];
    int MA, MB;
    stageA(0); stageA(1);
    issueV(0, VA, MA);
    issueV(1, VB, MB);

    for (int kt = 0; kt < 26; kt += 2) {
        __syncthreads();                     // drains group-(kt,kt+1) stages + V
        stageA(kt+2);                        // kt+2 <= 26 always (kt <= 24)
        if (kt+3 <= 26) stageA(kt+3);
        // tap kt
        {
            shortx8 b0 = reduceT(VA[0], 0, MA);
            shortx8 b1 = reduceT(VA[1], 1, MA);
            issueV(kt+2, VA, MA);            // refill slot A
            mfmaTap(kt, b0, b1);
        }
        // tap kt+1
        {
            shortx8 b0 = reduceT(VB[0], 0, MB);
            shortx8 b1 = reduceT(VB[1], 1, MB);
            if (kt+3 <= 26) issueV(kt+3, VB, MB);
            mfmaTap(kt+1, b0, b1);
        }
    }
    // tail: tap 26 (staged at kt=24 group; V issued at kt=24 group)
    __syncthreads();
    {
        shortx8 b0 = reduceT(VA[0], 0, MA);
        shortx8 b1 = reduceT(VA[1], 1, MA);
        mfmaTap(26, b0, b1);
    }

    #pragma unroll
    for (int i = 0; i < 4; ++i) {
        #pragma unroll
        for (int r = 0; r < 4; ++r) {
            int co = i*16 + lq*4 + r;
            y2n[(size_t)co*P_ + p] = f2b(acc[i][r] + bias[co]);
        }
    }
}

// ---------------------------------------------------------------------------
// BN1 stats from y1t [N*P][64]: partial sums per 512-row block, then finalize
// ---------------------------------------------------------------------------
__global__ __launch_bounds__(256) void stats_partial_kernel(
    const unsigned short* __restrict__ y1t, float* __restrict__ part)
{
    int b = blockIdx.x, tid = threadIdx.x;
    int c = tid & 63, sub = tid >> 6;
    float s = 0.f, q = 0.f;
    for (int rr = 0; rr < 128; ++rr) {
        int row = b*512 + sub*128 + rr;
        float v = b2f(y1t[(size_t)row*C_ + c]);
        s += v;
        q = fmaf(v, v, q);
    }
    __shared__ float ss[256], qq[256];
    ss[tid] = s; qq[tid] = q;
    __syncthreads();
    if (tid < 64) {
        float S = ss[tid] + ss[64+tid] + ss[128+tid] + ss[192+tid];
        float Q = qq[tid] + qq[64+tid] + qq[128+tid] + qq[192+tid];
        part[b*128 + tid]      = S;
        part[b*128 + 64 + tid] = Q;
    }
}

__global__ void stats_final_kernel(
    const float* __restrict__ part,
    const float* __restrict__ gamma, const float* __restrict__ beta,
    float* __restrict__ st1)
{
    int c = threadIdx.x;  // 64 threads
    float S = 0.f, Q = 0.f;
    for (int b = 0; b < 98; ++b) {
        S += part[b*128 + c];
        Q += part[b*128 + 64 + c];
    }
    const float inv = 1.f / (float)(N_*P_);
    float m = S * inv;
    float var = Q * inv - m*m;
    float scale = rsqrtf(var + 1e-5f) * gamma[c];
    st1[c]      = scale;
    st1[64 + c] = beta[c] - m*scale;
}

// ---------------------------------------------------------------------------
__global__ __launch_bounds__(256) void bn_stats_kernel(
    const unsigned short* __restrict__ src, float* __restrict__ stats)
{
    int c   = blockIdx.x;
    int tid = threadIdx.x;
    float s = 0.f, q = 0.f;
    for (int n = 0; n < N_; ++n) {
        const unsigned short* p = src + ((size_t)n*C_ + c)*P_;
        for (int i = tid; i < P_; i += 256) {
            float v = b2f(p[i]);
            s += v;
            q = fmaf(v, v, q);
        }
    }
    #pragma unroll
    for (int o = 32; o; o >>= 1) {
        s += __shfl_down(s, o);
        q += __shfl_down(q, o);
    }
    __shared__ float sh[2][4];
    int wave = tid >> 6;
    if ((tid & 63) == 0) { sh[0][wave] = s; sh[1][wave] = q; }
    __syncthreads();
    if (tid == 0) {
        float S = sh[0][0] + sh[0][1] + sh[0][2] + sh[0][3];
        float Q = sh[1][0] + sh[1][1] + sh[1][2] + sh[1][3];
        const float inv = 1.f / (float)(N_*P_);
        float m  = S * inv;
        float var = Q * inv - m*m;
        stats[c]      = m;
        stats[C_ + c] = rsqrtf(var + 1e-5f);
    }
}

__global__ __launch_bounds__(256) void bn_add_relu_kernel(
    const unsigned short* __restrict__ y2, const float* __restrict__ x,
    const float* __restrict__ stats,
    const float* __restrict__ gamma, const float* __restrict__ beta,
    float* __restrict__ out)
{
    size_t idx = (size_t)blockIdx.x*256 + threadIdx.x;
    int c = (int)((idx / P_) % C_);
    float v = (b2f(y2[idx]) - stats[c]) * stats[C_ + c] * gamma[c] + beta[c] + x[idx];
    out[idx] = fmaxf(v, 0.f);
}

// ---------------------------------------------------------------------------
extern "C" void kernel_launch(void* const* d_in, const int* in_sizes, int n_in,
                              void* d_out, int out_size, void* d_ws, size_t ws_size,
                              hipStream_t stream) {
    const float* x     = (const float*)d_in[0];
    const float* w_off = (const float*)d_in[1];
    const float* b_off = (const float*)d_in[2];
    const float* w1    = (const float*)d_in[3];
    const float* g1    = (const float*)d_in[4];
    const float* be1   = (const float*)d_in[5];
    const float* w2    = (const float*)d_in[6];
    const float* b2    = (const float*)d_in[7];
    const float* g2    = (const float*)d_in[8];
    const float* be2   = (const float*)d_in[9];
    float* out = (float*)d_out;

    // workspace (~88 MB)
    float* st1  = (float*)d_ws;                              // 128 (scale/shift)
    float* st2  = st1 + 128;                                 // 128 (mean/rstd)
    float* part = st2 + 128;                                 // 98*128
    unsigned short* off2 = (unsigned short*)(part + 98*128); // N*216*P*3 bf16 (65 MB)
    unsigned short* xt  = off2 + (size_t)N_*216*P_*3;        // N*P*64 bf16 (6.4 MB)
    unsigned short* y1t = xt  + (size_t)N_*P_*C_;            // N*P*64 bf16 (6.4 MB)
    unsigned short* y2  = y1t + (size_t)N_*P_*C_;            // N*64*P bf16 (6.4 MB)
    unsigned short* A1k = y2  + (size_t)N_*C_*P_;            // 768*1728 bf16 (2.65 MB)
    unsigned short* A1t = A1k + (size_t)MP_*KK_;             // 64*1728 bf16
    unsigned short* A2t = A1t + (size_t)C_*KK_;              // 64*1728 bf16

    // prep
    transpose_xt_kernel<<<N_*(P_/64), 256, 0, stream>>>(x, xt);
    permA1k_kernel<<<(MP_*KK_+255)/256, 256, 0, stream>>>(w_off, A1k);
    perm_w_kernel<<<(C_*KK_+255)/256, 256, 0, stream>>>(w1, A1t);
    perm_w_kernel<<<(C_*KK_+255)/256, 256, 0, stream>>>(w2, A2t);

    // conv_off fused -> off2 (both n): main 128x256 tiles + tail (640..647)
    conv_off_fused<<<2*490, 256, 0, stream>>>(A1k, xt, b_off, off2);
    conv_off_tail<<<2*196, 256, 0, stream>>>(A1k, xt, b_off, off2);

    // deform fused -> y1t (both n), single-barrier dbuf pipeline
    deform_fused<<<N_*(P_/32), 256, 0, stream>>>(xt, off2, A1t, y1t);

    // BN1 scale/shift
    stats_partial_kernel<<<98, 256, 0, stream>>>(y1t, part);
    stats_final_kernel<<<1, 64, 0, stream>>>(part, g1, be1, st1);

    // conv2 fused (BN1+ReLU on read) -> y2 (both n), 2-tap groups
    conv2_fused<<<N_*(P_/64), 256, 0, stream>>>(y1t, st1, A2t, b2, y2);

    // BN2 + residual + ReLU -> out (fp32)
    bn_stats_kernel<<<C_, 256, 0, stream>>>(y2, st2);
    bn_add_relu_kernel<<<(N_*C_*P_)/256, 256, 0, stream>>>(y2, x, st2, g2, be2, out);
}

// Round 8
// 466.984 us; speedup vs baseline: 1.1134x; 1.1134x over previous
//
#include <hip/hip_runtime.h>
#include <hip/hip_bf16.h>

#define N_ 2
#define C_ 64
#define D_ 8
#define H_ 56
#define W_ 56
#define HW_ (H_*W_)        // 3136
#define P_ (D_*HW_)        // 25088
#define G_ 8
#define CPG_ 8
#define K_ 27
#define CO_OFF_ 648        // G * 3 * K
#define MP_ 768            // conv_off M padded (rows 648+ zero)
#define KK_ 1728           // GEMM K dim (= 27*64, k-major: ktap*64 + ci)
#define KB_ (KK_*2)        // bytes per bf16 row

typedef __attribute__((ext_vector_type(8))) short shortx8;
typedef __attribute__((ext_vector_type(4))) float floatx4;
#define AS1 __attribute__((address_space(1)))
#define AS3 __attribute__((address_space(3)))

__device__ inline float b2f(unsigned short u) {
    union { unsigned u; float f; } x; x.u = ((unsigned)u) << 16; return x.f;
}
__device__ inline unsigned short f2b(float f) {
    union { float f; unsigned u; } x; x.f = f;
    unsigned r = (x.u + 0x7fffu + ((x.u >> 16) & 1u)) >> 16;   // RNE
    return (unsigned short)r;
}
__device__ inline float lof(unsigned u) { union { unsigned u; float f; } x; x.u = u << 16; return x.f; }
__device__ inline float hif(unsigned u) { union { unsigned u; float f; } x; x.u = u & 0xffff0000u; return x.f; }
// HW packed f32->bf16 (RNE), 1 inst for 2 values.
__device__ inline unsigned cvt_pk_bf16(float a, float b) {
    unsigned r;
    asm("v_cvt_pk_bf16_f32 %0, %1, %2" : "=v"(r) : "v"(a), "v"(b));
    return r;
}

// off layout: off2[(g*27+kt)*P + p][3] bf16 (interleaved comps, 65 MB total)

// ---------------------------------------------------------------------------
// x [N][64][P] fp32 -> xt [N][P][64] bf16  (64p x 64c LDS tile transpose)
// ---------------------------------------------------------------------------
__global__ __launch_bounds__(256) void transpose_xt_kernel(
    const float* __restrict__ x, unsigned short* __restrict__ xt)
{
    __shared__ unsigned short tile[64][65];
    int b  = blockIdx.x;
    int n  = b / (P_/64);
    int p0 = (b % (P_/64))*64;
    int tid = threadIdx.x;
    int j  = tid & 63;
    int c0 = (tid >> 6)*16;
    for (int r = 0; r < 16; ++r)
        tile[c0 + r][j] = f2b(x[((size_t)n*C_ + c0 + r)*P_ + p0 + j]);
    __syncthreads();
    unsigned* dst = (unsigned*)(xt + ((size_t)n*P_ + p0)*C_);
    #pragma unroll
    for (int it = 0; it < 8; ++it) {
        int wi  = it*256 + tid;
        int row = wi >> 5;
        int c   = (wi & 31)*2;
        unsigned lo = tile[c][row], hi = tile[c+1][row];
        dst[(size_t)row*32 + (wi & 31)] = lo | (hi << 16);
    }
}

// w_off [648][64][27] fp32 -> A1k [768][kk*64+ci] bf16 (k-major, zero-pad rows)
__global__ __launch_bounds__(256) void permA1k_kernel(
    const float* __restrict__ w, unsigned short* __restrict__ A)
{
    int i = blockIdx.x*256 + threadIdx.x;
    if (i >= MP_*KK_) return;
    int m = i / KK_, r = i % KK_;
    int kk = r / 64, ci = r % 64;
    A[i] = (m < CO_OFF_) ? f2b(w[((size_t)m*C_ + ci)*K_ + kk]) : (unsigned short)0;
}

// w [O=64][I=64][27] fp32 -> At[o][k*64+i] bf16 (k-major)
__global__ __launch_bounds__(256) void perm_w_kernel(
    const float* __restrict__ w, unsigned short* __restrict__ At)
{
    int tid = blockIdx.x*256 + threadIdx.x;
    if (tid >= C_*KK_) return;
    int o  = tid / KK_;
    int r  = tid % KK_;
    int k  = r / 64, i = r % 64;
    At[tid] = f2b(w[((size_t)o*C_ + i)*K_ + k]);
}

// ---------------------------------------------------------------------------
// conv_off fused v3: MERGED main (128m x 256p, blocks 0..979) + tail (rows
// 640..647, blocks 980..1371) in ONE launch so tail blocks fill CU gaps
// instead of running serially after main. Shared LDS buffer aliased per path.
// ---------------------------------------------------------------------------
__global__ __launch_bounds__(256, 2) void conv_off_fused(
    const unsigned short* __restrict__ A,    // A1k [768][1728]
    const unsigned short* __restrict__ xt,   // [N][P][64] bf16
    const float* __restrict__ bias,          // [648]
    unsigned short* __restrict__ off2)       // [N][216*P][3] bf16
{
    __shared__ __align__(16) short SH[35840];   // 71,680 B: max(main 64KB, tail 70KB)
    int tid = threadIdx.x;
    int w = tid >> 6, lane = tid & 63;
    int lm = lane & 15, lq = lane >> 4;

    if (blockIdx.x < 2*490) {
        // ---------------- main path: 128m x 256p ----------------
        short* As0 = SH;                 // As[2][16*512]
        short* Bs  = SH + 2*16*512;      // Bs[32*512]
        int n   = blockIdx.x / 490;
        int bid = blockIdx.x % 490;
        int mt = bid / 98, nt = bid % 98;
        int m0 = mt*128, p0 = nt*256;

        const unsigned short* xtn = xt + (size_t)n*P_*C_;
        unsigned short* out2 = off2 + (size_t)n*216*P_*3;

        const char* Ab0 = (const char*)A + (size_t)(m0 + w*32 + lm)*KB_ + lq*16;
        const char* Ab1 = Ab0 + (size_t)16*KB_;

        int oct = lane & 7;
        int prj[8], dj[8], hj[8], wj[8];
        #pragma unroll
        for (int j = 0; j < 8; ++j) {
            int prow = j*32 + w*8 + (lane >> 3);
            prj[j] = prow;
            int p = p0 + prow;
            dj[j] = p / HW_;
            int hw2 = p % HW_;
            hj[j] = hw2 / W_;
            wj[j] = hw2 % W_;
        }

        auto stageA = [&](int kt, int buf) {
            __builtin_amdgcn_global_load_lds((const AS1 unsigned*)(Ab0 + kt*128),      (AS3 unsigned*)(As0 + buf*8192 + (w*2)*512),     16, 0, 0);
            __builtin_amdgcn_global_load_lds((const AS1 unsigned*)(Ab1 + kt*128),      (AS3 unsigned*)(As0 + buf*8192 + (w*2+1)*512),   16, 0, 0);
            __builtin_amdgcn_global_load_lds((const AS1 unsigned*)(Ab0 + kt*128 + 64), (AS3 unsigned*)(As0 + buf*8192 + (8+w*2)*512),   16, 0, 0);
            __builtin_amdgcn_global_load_lds((const AS1 unsigned*)(Ab1 + kt*128 + 64), (AS3 unsigned*)(As0 + buf*8192 + (8+w*2+1)*512), 16, 0, 0);
        };
        auto loadB = [&](int kt, uint4* B) {
            int kd = kt/9 - 1, kh = (kt/3)%3 - 1, kw = kt%3 - 1;
            int delta = kd*HW_ + kh*W_ + kw;
            #pragma unroll
            for (int j = 0; j < 8; ++j) {
                bool v = ((unsigned)(dj[j]+kd) < (unsigned)D_) &&
                         ((unsigned)(hj[j]+kh) < (unsigned)H_) &&
                         ((unsigned)(wj[j]+kw) < (unsigned)W_);
                uint4 val = {0u,0u,0u,0u};
                if (v) val = *(const uint4*)(xtn + (size_t)(p0 + prj[j] + delta)*C_ + oct*8);
                B[j] = val;
            }
        };

        int mh = w >> 1, nh = w & 1;
        floatx4 acc[4][8];
        #pragma unroll
        for (int i = 0; i < 4; ++i)
            #pragma unroll
            for (int j = 0; j < 8; ++j)
                acc[i][j] = (floatx4){0.f, 0.f, 0.f, 0.f};

        uint4 Bcur[8], Bnext[8];
        #pragma unroll
        for (int j = 0; j < 8; ++j) Bnext[j] = (uint4){0u,0u,0u,0u};
        stageA(0, 0);
        loadB(0, Bcur);

        for (int kt = 0; kt < 27; ++kt) {
            int buf = kt & 1;
            __syncthreads();
            #pragma unroll
            for (int j = 0; j < 8; ++j) {
                int chunk = (oct>>2)*16 + (prj[j]>>4);
                *(uint4*)&Bs[chunk*512 + ((oct&3)*16 + ((prj[j]&15) ^ oct))*8] = Bcur[j];
            }
            __syncthreads();
            if (kt < 26) { stageA(kt+1, buf^1); loadB(kt+1, Bnext); }
            #pragma unroll
            for (int ks = 0; ks < 2; ++ks) {
                int swzB = (lq*16 + (lm ^ (ks*4 + lq)))*8;
                shortx8 a[4];
                #pragma unroll
                for (int i = 0; i < 4; ++i) a[i] = *(const shortx8*)&As0[buf*8192 + (ks*8 + 4*mh + i)*512 + lane*8];
                #pragma unroll
                for (int j = 0; j < 8; ++j) {
                    shortx8 b = *(const shortx8*)&Bs[(ks*16 + 8*nh + j)*512 + swzB];
                    #pragma unroll
                    for (int i = 0; i < 4; ++i)
                        acc[i][j] = __builtin_amdgcn_mfma_f32_16x16x32_bf16(a[i], b, acc[i][j], 0, 0, 0);
                }
            }
            #pragma unroll
            for (int j = 0; j < 8; ++j) Bcur[j] = Bnext[j];
        }

        #pragma unroll
        for (int i = 0; i < 4; ++i) {
            int cob = m0 + (4*mh+i)*16 + lq*4;
            #pragma unroll
            for (int r = 0; r < 4; ++r) {
                int co = cob + r;    // < 640 always (mt <= 4)
                float bv = bias[co];
                int row2 = co / 3, comp = co % 3;
                size_t base = (size_t)row2*P_*3 + comp;
                #pragma unroll
                for (int j = 0; j < 8; ++j) {
                    int col = p0 + (8*nh+j)*16 + lm;
                    out2[base + (size_t)col*3] = f2b(acc[i][j][r] + bv);
                }
            }
        }
    } else {
        // ---------------- tail path: rows 640..647, 16x128 tile ----------------
        short* As = SH;                  // 54*512 shorts
        short* Bs = SH + 54*512;         // 16*512 shorts
        int t  = blockIdx.x - 2*490;
        int n  = t / 196;
        int p0 = (t % 196)*128;

        const unsigned short* xtn = xt + (size_t)n*P_*C_;
        unsigned short* out2 = off2 + (size_t)n*216*P_*3;

        const char* Abase = (const char*)A + (size_t)(640 + lm)*KB_ + lq*16;
        for (int ch = w; ch < 54; ch += 4)
            __builtin_amdgcn_global_load_lds((const AS1 unsigned*)(Abase + ch*64),
                                             (AS3 unsigned*)(As + ch*512), 16, 0, 0);

        int oct = lane & 7;
        int prj[4], dj[4], hj[4], wj[4];
        #pragma unroll
        for (int j = 0; j < 4; ++j) {
            int prow = j*32 + w*8 + (lane >> 3);
            prj[j] = prow;
            int p = p0 + prow;
            dj[j] = p / HW_;
            int hw2 = p % HW_;
            hj[j] = hw2 / W_;
            wj[j] = hw2 % W_;
        }
        auto loadB = [&](int kt, uint4* B) {
            int kd = kt/9 - 1, kh = (kt/3)%3 - 1, kw = kt%3 - 1;
            int delta = kd*HW_ + kh*W_ + kw;
            #pragma unroll
            for (int j = 0; j < 4; ++j) {
                bool v = ((unsigned)(dj[j]+kd) < (unsigned)D_) &&
                         ((unsigned)(hj[j]+kh) < (unsigned)H_) &&
                         ((unsigned)(wj[j]+kw) < (unsigned)W_);
                uint4 val = {0u,0u,0u,0u};
                if (v) val = *(const uint4*)(xtn + (size_t)(p0 + prj[j] + delta)*C_ + oct*8);
                B[j] = val;
            }
        };

        floatx4 acc[2];
        acc[0] = (floatx4){0.f,0.f,0.f,0.f};
        acc[1] = (floatx4){0.f,0.f,0.f,0.f};

        uint4 Bcur[4], Bnext[4];
        #pragma unroll
        for (int j = 0; j < 4; ++j) Bnext[j] = (uint4){0u,0u,0u,0u};
        loadB(0, Bcur);

        for (int kt = 0; kt < 27; ++kt) {
            __syncthreads();
            #pragma unroll
            for (int j = 0; j < 4; ++j) {
                int chunk = (oct>>2)*8 + (prj[j]>>4);
                *(uint4*)&Bs[chunk*512 + ((oct&3)*16 + ((prj[j]&15) ^ oct))*8] = Bcur[j];
            }
            __syncthreads();
            if (kt < 26) loadB(kt+1, Bnext);
            #pragma unroll
            for (int ks = 0; ks < 2; ++ks) {
                int swzB = (lq*16 + (lm ^ (ks*4 + lq)))*8;
                shortx8 a = *(const shortx8*)&As[(kt*2 + ks)*512 + lane*8];
                #pragma unroll
                for (int j = 0; j < 2; ++j) {
                    shortx8 b = *(const shortx8*)&Bs[(ks*8 + w*2 + j)*512 + swzB];
                    acc[j] = __builtin_amdgcn_mfma_f32_16x16x32_bf16(a, b, acc[j], 0, 0, 0);
                }
            }
            #pragma unroll
            for (int j = 0; j < 4; ++j) Bcur[j] = Bnext[j];
        }

        #pragma unroll
        for (int j = 0; j < 2; ++j) {
            #pragma unroll
            for (int r = 0; r < 4; ++r) {
                int co = 640 + lq*4 + r;
                if (co < CO_OFF_) {
                    int col = p0 + w*32 + j*16 + lm;
                    out2[((size_t)(co/3)*P_ + col)*3 + (co%3)] = f2b(acc[j][r] + bias[co]);
                }
            }
        }
    }
}

// ---------------------------------------------------------------------------
// deform fused (R6 known-good, ~172 us): N=32 tiles, A dbuf + B dbuf in LDS
// -> ONE barrier per kt; gather pipeline inside the tap.
// ---------------------------------------------------------------------------
__global__ __launch_bounds__(256) void deform_fused(
    const unsigned short* __restrict__ xt,   // [N][P][64] bf16
    const unsigned short* __restrict__ off2, // [N][216*P][3] bf16
    const unsigned short* __restrict__ A,    // A1t [64][1728]
    unsigned short* __restrict__ y1t)        // [N][P][64] bf16
{
    __shared__ __align__(16) short SH[12288]; // A dbuf 2x4096, B dbuf 2x2048
    int tid = threadIdx.x;
    int w = tid >> 6, lane = tid & 63;
    int n  = blockIdx.x / (P_/32);
    int p0 = (blockIdx.x % (P_/32))*32;
    int lm = lane & 15, lq = lane >> 4;

    const unsigned short* offn = off2 + (size_t)n*216*P_*3;
    const uint4* xg0 = (const uint4*)(xt + (size_t)n*P_*C_);

    const char* Ab = (const char*)A + (size_t)(w*16 + lm)*KB_ + lq*16;

    int g = lane & 7;
    int prow = tid >> 3;          // 0..31
    int p = p0 + prow;
    int dd = p / HW_;
    int hw2 = p % HW_;
    int hh = hw2 / W_;
    int ww = hw2 % W_;
    int bchunk = (g>>2)*2 + (prow>>4);
    int boffs  = ((g&3)*16 + ((prow&15) ^ g))*8;

    auto stageA = [&](int kt, int buf) {
        __builtin_amdgcn_global_load_lds((const AS1 unsigned*)(Ab + kt*128),      (AS3 unsigned*)(SH + buf*4096 + w*512),     16, 0, 0);
        __builtin_amdgcn_global_load_lds((const AS1 unsigned*)(Ab + kt*128 + 64), (AS3 unsigned*)(SH + buf*4096 + (4+w)*512), 16, 0, 0);
    };
    auto loadOff = [&](int kt, float* o) {
        size_t idx = ((size_t)(g*K_ + kt)*P_ + p)*3;
        o[0] = b2f(offn[idx]);
        o[1] = b2f(offn[idx + 1]);
        o[2] = b2f(offn[idx + 2]);
    };
    auto issueCorners = [&](int kt, float* o, uint4* V, float* Wt) {
        int kd = kt/9 - 1, kh = (kt/3)%3 - 1, kw = kt%3 - 1;
        float pd = (float)(dd + kd) + o[0];
        float ph = (float)(hh + kh) + o[1];
        float pw = (float)(ww + kw) + o[2];
        float fd0 = floorf(pd), fh0 = floorf(ph), fw0 = floorf(pw);
        int d0 = (int)fd0, h0 = (int)fh0, w0i = (int)fw0;
        float fd = pd - fd0, fh = ph - fh0, fw = pw - fw0;
        int dc0 = min(max(d0, 0), D_-1),   dc1 = min(max(d0+1, 0), D_-1);
        int hc0 = min(max(h0, 0), H_-1),   hc1 = min(max(h0+1, 0), H_-1);
        int wc0 = min(max(w0i, 0), W_-1),  wc1 = min(max(w0i+1, 0), W_-1);
        float wd0 = ((unsigned)d0      < (unsigned)D_) ? 1.f - fd : 0.f;
        float wd1 = ((unsigned)(d0+1)  < (unsigned)D_) ? fd       : 0.f;
        float wh0 = ((unsigned)h0      < (unsigned)H_) ? 1.f - fh : 0.f;
        float wh1 = ((unsigned)(h0+1)  < (unsigned)H_) ? fh       : 0.f;
        float ww0 = ((unsigned)w0i     < (unsigned)W_) ? 1.f - fw : 0.f;
        float ww1 = ((unsigned)(w0i+1) < (unsigned)W_) ? fw       : 0.f;
        int rb00 = (dc0*H_ + hc0)*W_, rb01 = (dc0*H_ + hc1)*W_;
        int rb10 = (dc1*H_ + hc0)*W_, rb11 = (dc1*H_ + hc1)*W_;
        float wdh00 = wd0*wh0, wdh01 = wd0*wh1, wdh10 = wd1*wh0, wdh11 = wd1*wh1;
        V[0] = xg0[(size_t)(rb00+wc0)*8 + g];  Wt[0] = wdh00*ww0;
        V[1] = xg0[(size_t)(rb00+wc1)*8 + g];  Wt[1] = wdh00*ww1;
        V[2] = xg0[(size_t)(rb01+wc0)*8 + g];  Wt[2] = wdh01*ww0;
        V[3] = xg0[(size_t)(rb01+wc1)*8 + g];  Wt[3] = wdh01*ww1;
        V[4] = xg0[(size_t)(rb10+wc0)*8 + g];  Wt[4] = wdh10*ww0;
        V[5] = xg0[(size_t)(rb10+wc1)*8 + g];  Wt[5] = wdh10*ww1;
        V[6] = xg0[(size_t)(rb11+wc0)*8 + g];  Wt[6] = wdh11*ww0;
        V[7] = xg0[(size_t)(rb11+wc1)*8 + g];  Wt[7] = wdh11*ww1;
    };
    auto reduceCorners = [&](uint4* V, float* Wt, uint4& o4) {
        float res[CPG_];
        #pragma unroll
        for (int c = 0; c < CPG_; ++c) res[c] = 0.f;
        #pragma unroll
        for (int c = 0; c < 8; ++c) {
            uint4 v4 = V[c];
            float wgt = Wt[c];
            res[0] = fmaf(wgt, lof(v4.x), res[0]);
            res[1] = fmaf(wgt, hif(v4.x), res[1]);
            res[2] = fmaf(wgt, lof(v4.y), res[2]);
            res[3] = fmaf(wgt, hif(v4.y), res[3]);
            res[4] = fmaf(wgt, lof(v4.z), res[4]);
            res[5] = fmaf(wgt, hif(v4.z), res[5]);
            res[6] = fmaf(wgt, lof(v4.w), res[6]);
            res[7] = fmaf(wgt, hif(v4.w), res[7]);
        }
        o4.x = cvt_pk_bf16(res[0], res[1]);
        o4.y = cvt_pk_bf16(res[2], res[3]);
        o4.z = cvt_pk_bf16(res[4], res[5]);
        o4.w = cvt_pk_bf16(res[6], res[7]);
    };

    int mh = w >> 1, nh = w & 1;
    floatx4 acc[2];
    acc[0] = (floatx4){0.f,0.f,0.f,0.f};
    acc[1] = (floatx4){0.f,0.f,0.f,0.f};

    float offA[3], offB[3], offT[3];
    uint4 Vv[8]; float Wt[8];
    uint4 o4cur;

    stageA(0, 0);
    loadOff(0, offA);
    loadOff(1, offB);
    issueCorners(0, offA, Vv, Wt);
    reduceCorners(Vv, Wt, o4cur);
    *(uint4*)&SH[8192 + bchunk*512 + boffs] = o4cur;   // B(0) -> Bs buf 0

    for (int kt = 0; kt < 27; ++kt) {
        int buf = kt & 1;
        __syncthreads();   // Bs[buf] writes + As[buf] staging drained
        if (kt < 26) {
            stageA(kt+1, buf^1);
            if (kt < 25) loadOff(kt+2, offT);
            issueCorners(kt+1, offB, Vv, Wt);
        }
        #pragma unroll
        for (int ks = 0; ks < 2; ++ks) {
            int swzB = (lq*16 + (lm ^ (ks*4 + lq)))*8;
            shortx8 b = *(const shortx8*)&SH[8192 + buf*2048 + (ks*2 + nh)*512 + swzB];
            #pragma unroll
            for (int i = 0; i < 2; ++i) {
                shortx8 a = *(const shortx8*)&SH[buf*4096 + (ks*4 + 2*mh+i)*512 + lane*8];
                acc[i] = __builtin_amdgcn_mfma_f32_16x16x32_bf16(a, b, acc[i], 0, 0, 0);
            }
        }
        if (kt < 26) {
            reduceCorners(Vv, Wt, o4cur);
            *(uint4*)&SH[8192 + (buf^1)*2048 + bchunk*512 + boffs] = o4cur;
            offB[0] = offT[0]; offB[1] = offT[1]; offB[2] = offT[2];
        }
    }

    // epilogue: transpose 64o x 32p tile to y1t[p][o] via LDS (stride 72)
    __syncthreads();
    #pragma unroll
    for (int i = 0; i < 2; ++i) {
        int ob = mh*32 + i*16 + lq*4;
        int pc = nh*16 + lm;
        #pragma unroll
        for (int rr = 0; rr < 4; ++rr)
            SH[pc*72 + ob + rr] = (short)f2b(acc[i][rr]);
    }
    __syncthreads();
    {
        int row = tid >> 3, seg = tid & 7;
        uint4 v = *(const uint4*)&SH[row*72 + seg*8];
        *(uint4*)(y1t + ((size_t)n*P_ + p0 + row)*C_ + seg*8) = v;
    }
}

// ---------------------------------------------------------------------------
// conv2 fused v4: quad-buffer core (R7) + BN2 partial sums in epilogue
// (replaces the whole bn_stats pass). Partials: shfl_xor over lm (16 p) then
// LDS reduce over 4 waves -> part2[blk][128].
// ---------------------------------------------------------------------------
__global__ __launch_bounds__(256) void conv2_fused(
    const unsigned short* __restrict__ y1t,  // [N][P][64] bf16
    const float* __restrict__ st1,           // [64] scale, [64] shift
    const unsigned short* __restrict__ A,    // A2t [64][1728]
    const float* __restrict__ bias,          // [64]
    unsigned short* __restrict__ y2,         // [N][64][P] bf16
    float* __restrict__ part2)               // [784][128] block partials
{
    __shared__ __align__(16) short As[4][4096];   // 32 KB quad-buffer
    __shared__ float sc[64], sf[64];
    __shared__ float SP[4][64], SQ[4][64];
    int tid = threadIdx.x;
    if (tid < 64) sc[tid] = st1[tid];
    else if (tid < 128) sf[tid-64] = st1[tid];
    int w = tid >> 6, lane = tid & 63;
    int n  = blockIdx.x / (P_/64);
    int p0 = (blockIdx.x % (P_/64))*64;
    int lm = lane & 15, lq = lane >> 4;

    const unsigned short* y1n = y1t + (size_t)n*P_*C_;
    unsigned short* y2n = y2 + (size_t)n*C_*P_;
    const char* Ab = (const char*)A + (size_t)(w*16 + lm)*KB_ + lq*16;

    int p = p0 + w*16 + lm;
    int dd = p / HW_, hw2 = p % HW_;
    int hh = hw2 / W_, ww = hw2 % W_;

    auto stageA = [&](int kt) {
        int buf = kt & 3;
        __builtin_amdgcn_global_load_lds((const AS1 unsigned*)(Ab + kt*128),      (AS3 unsigned*)(&As[buf][w*512]),     16, 0, 0);
        __builtin_amdgcn_global_load_lds((const AS1 unsigned*)(Ab + kt*128 + 64), (AS3 unsigned*)(&As[buf][(4+w)*512]), 16, 0, 0);
    };
    auto issueV = [&](int kt, uint4* V, int& M) {
        int kd = kt/9 - 1, kh = (kt/3)%3 - 1, kw = kt%3 - 1;
        int delta = kd*HW_ + kh*W_ + kw;
        bool v = ((unsigned)(dd+kd) < (unsigned)D_) &&
                 ((unsigned)(hh+kh) < (unsigned)H_) &&
                 ((unsigned)(ww+kw) < (unsigned)W_);
        M = v ? 1 : 0;
        #pragma unroll
        for (int ks = 0; ks < 2; ++ks) {
            uint4 val = {0u,0u,0u,0u};
            if (v) val = *(const uint4*)(y1n + (size_t)(p + delta)*C_ + (ks*4 + lq)*8);
            V[ks] = val;
        }
    };
    auto reduceT = [&](uint4 V, int ks, int M) -> shortx8 {
        uint4 o4 = {0u,0u,0u,0u};
        if (M) {
            int cb = (ks*4 + lq)*8;
            float r0 = fmaxf(lof(V.x)*sc[cb+0] + sf[cb+0], 0.f);
            float r1 = fmaxf(hif(V.x)*sc[cb+1] + sf[cb+1], 0.f);
            float r2 = fmaxf(lof(V.y)*sc[cb+2] + sf[cb+2], 0.f);
            float r3 = fmaxf(hif(V.y)*sc[cb+3] + sf[cb+3], 0.f);
            float r4 = fmaxf(lof(V.z)*sc[cb+4] + sf[cb+4], 0.f);
            float r5 = fmaxf(hif(V.z)*sc[cb+5] + sf[cb+5], 0.f);
            float r6 = fmaxf(lof(V.w)*sc[cb+6] + sf[cb+6], 0.f);
            float r7 = fmaxf(hif(V.w)*sc[cb+7] + sf[cb+7], 0.f);
            o4.x = cvt_pk_bf16(r0, r1);
            o4.y = cvt_pk_bf16(r2, r3);
            o4.z = cvt_pk_bf16(r4, r5);
            o4.w = cvt_pk_bf16(r6, r7);
        }
        return *(shortx8*)&o4;
    };

    floatx4 acc[4];
    #pragma unroll
    for (int i = 0; i < 4; ++i) acc[i] = (floatx4){0.f,0.f,0.f,0.f};

    auto mfmaTap = [&](int kt, shortx8 b0, shortx8 b1) {
        int buf = kt & 3;
        #pragma unroll
        for (int i = 0; i < 4; ++i) {
            shortx8 a = *(const shortx8*)&As[buf][(0*4 + i)*512 + lane*8];
            acc[i] = __builtin_amdgcn_mfma_f32_16x16x32_bf16(a, b0, acc[i], 0, 0, 0);
        }
        #pragma unroll
        for (int i = 0; i < 4; ++i) {
            shortx8 a = *(const shortx8*)&As[buf][(1*4 + i)*512 + lane*8];
            acc[i] = __builtin_amdgcn_mfma_f32_16x16x32_bf16(a, b1, acc[i], 0, 0, 0);
        }
    };

    uint4 VA[2], VB[2];
    int MA, MB;
    stageA(0); stageA(1);
    issueV(0, VA, MA);
    issueV(1, VB, MB);

    for (int kt = 0; kt < 26; kt += 2) {
        __syncthreads();
        stageA(kt+2);
        if (kt+3 <= 26) stageA(kt+3);
        {
            shortx8 b0 = reduceT(VA[0], 0, MA);
            shortx8 b1 = reduceT(VA[1], 1, MA);
            issueV(kt+2, VA, MA);
            mfmaTap(kt, b0, b1);
        }
        {
            shortx8 b0 = reduceT(VB[0], 0, MB);
            shortx8 b1 = reduceT(VB[1], 1, MB);
            if (kt+3 <= 26) issueV(kt+3, VB, MB);
            mfmaTap(kt+1, b0, b1);
        }
    }
    __syncthreads();
    {
        shortx8 b0 = reduceT(VA[0], 0, MA);
        shortx8 b1 = reduceT(VA[1], 1, MA);
        mfmaTap(26, b0, b1);
    }

    // epilogue: y2 write + BN2 partials (sum, sumsq per channel over 64 p)
    #pragma unroll
    for (int i = 0; i < 4; ++i) {
        #pragma unroll
        for (int r = 0; r < 4; ++r) {
            int co = i*16 + lq*4 + r;
            float v = acc[i][r] + bias[co];
            y2n[(size_t)co*P_ + p] = f2b(v);
            float s = v, q = v*v;
            #pragma unroll
            for (int m = 1; m < 16; m <<= 1) {
                s += __shfl_xor(s, m);
                q += __shfl_xor(q, m);
            }
            if (lm == 0) { SP[w][co] = s; SQ[w][co] = q; }
        }
    }
    __syncthreads();
    if (tid < 64) {
        float S = SP[0][tid] + SP[1][tid] + SP[2][tid] + SP[3][tid];
        float Q = SQ[0][tid] + SQ[1][tid] + SQ[2][tid] + SQ[3][tid];
        part2[(size_t)blockIdx.x*128 + tid]      = S;
        part2[(size_t)blockIdx.x*128 + 64 + tid] = Q;
    }
}

// ---------------------------------------------------------------------------
// BN1 stats from y1t [N*P][64]: partial sums per 512-row block, then finalize
// ---------------------------------------------------------------------------
__global__ __launch_bounds__(256) void stats_partial_kernel(
    const unsigned short* __restrict__ y1t, float* __restrict__ part)
{
    int b = blockIdx.x, tid = threadIdx.x;
    int c = tid & 63, sub = tid >> 6;
    float s = 0.f, q = 0.f;
    for (int rr = 0; rr < 128; ++rr) {
        int row = b*512 + sub*128 + rr;
        float v = b2f(y1t[(size_t)row*C_ + c]);
        s += v;
        q = fmaf(v, v, q);
    }
    __shared__ float ss[256], qq[256];
    ss[tid] = s; qq[tid] = q;
    __syncthreads();
    if (tid < 64) {
        float S = ss[tid] + ss[64+tid] + ss[128+tid] + ss[192+tid];
        float Q = qq[tid] + qq[64+tid] + qq[128+tid] + qq[192+tid];
        part[b*128 + tid]      = S;
        part[b*128 + 64 + tid] = Q;
    }
}

__global__ void stats_final_kernel(
    const float* __restrict__ part,
    const float* __restrict__ gamma, const float* __restrict__ beta,
    float* __restrict__ st1)
{
    int c = threadIdx.x;  // 64 threads
    float S = 0.f, Q = 0.f;
    for (int b = 0; b < 98; ++b) {
        S += part[b*128 + c];
        Q += part[b*128 + 64 + c];
    }
    const float inv = 1.f / (float)(N_*P_);
    float m = S * inv;
    float var = Q * inv - m*m;
    float scale = rsqrtf(var + 1e-5f) * gamma[c];
    st1[c]      = scale;
    st1[64 + c] = beta[c] - m*scale;
}

// ---------------------------------------------------------------------------
// BN2 finalize from conv2 partials -> st2 (scale, shift)
// ---------------------------------------------------------------------------
__global__ __launch_bounds__(256) void bn2_final_kernel(
    const float* __restrict__ part2,
    const float* __restrict__ gamma, const float* __restrict__ beta,
    float* __restrict__ st2)
{
    int tid = threadIdx.x;          // 256
    int c = tid & 63, seg = tid >> 6;
    float S = 0.f, Q = 0.f;
    for (int b = seg*196; b < seg*196 + 196; ++b) {
        S += part2[(size_t)b*128 + c];
        Q += part2[(size_t)b*128 + 64 + c];
    }
    __shared__ float ss[256], qq[256];
    ss[tid] = S; qq[tid] = Q;
    __syncthreads();
    if (tid < 64) {
        float St = ss[tid] + ss[64+tid] + ss[128+tid] + ss[192+tid];
        float Qt = qq[tid] + qq[64+tid] + qq[128+tid] + qq[192+tid];
        const float inv = 1.f / (float)(N_*P_);
        float m = St * inv;
        float var = Qt * inv - m*m;
        float scale = rsqrtf(var + 1e-5f) * gamma[tid];
        st2[tid]      = scale;
        st2[64 + tid] = beta[tid] - m*scale;
    }
}

// ---------------------------------------------------------------------------
// BN2 apply + residual + ReLU, vectorized x4 (uint2 y2 / float4 x,out)
// ---------------------------------------------------------------------------
__global__ __launch_bounds__(256) void bn_add_relu_kernel(
    const unsigned short* __restrict__ y2, const float* __restrict__ x,
    const float* __restrict__ st2, float* __restrict__ out)
{
    size_t i4 = ((size_t)blockIdx.x*256 + threadIdx.x)*4;
    int c = (int)((i4 / P_) % C_);
    float scale = st2[c], shift = st2[64 + c];
    uint2 yv = *(const uint2*)(y2 + i4);
    float4 xv = *(const float4*)(x + i4);
    float4 o;
    o.x = fmaxf(fmaf(lof(yv.x), scale, shift) + xv.x, 0.f);
    o.y = fmaxf(fmaf(hif(yv.x), scale, shift) + xv.y, 0.f);
    o.z = fmaxf(fmaf(lof(yv.y), scale, shift) + xv.z, 0.f);
    o.w = fmaxf(fmaf(hif(yv.y), scale, shift) + xv.w, 0.f);
    *(float4*)(out + i4) = o;
}

// ---------------------------------------------------------------------------
extern "C" void kernel_launch(void* const* d_in, const int* in_sizes, int n_in,
                              void* d_out, int out_size, void* d_ws, size_t ws_size,
                              hipStream_t stream) {
    const float* x     = (const float*)d_in[0];
    const float* w_off = (const float*)d_in[1];
    const float* b_off = (const float*)d_in[2];
    const float* w1    = (const float*)d_in[3];
    const float* g1    = (const float*)d_in[4];
    const float* be1   = (const float*)d_in[5];
    const float* w2    = (const float*)d_in[6];
    const float* b2    = (const float*)d_in[7];
    const float* g2    = (const float*)d_in[8];
    const float* be2   = (const float*)d_in[9];
    float* out = (float*)d_out;

    // workspace (~88 MB)
    float* st1  = (float*)d_ws;                              // 128 (scale/shift BN1)
    float* st2  = st1 + 128;                                 // 128 (scale/shift BN2)
    float* part = st2 + 128;                                 // 98*128
    unsigned short* off2 = (unsigned short*)(part + 98*128); // N*216*P*3 bf16 (65 MB)
    unsigned short* xt  = off2 + (size_t)N_*216*P_*3;        // N*P*64 bf16 (6.4 MB)
    unsigned short* y1t = xt  + (size_t)N_*P_*C_;            // N*P*64 bf16 (6.4 MB)
    unsigned short* y2  = y1t + (size_t)N_*P_*C_;            // N*64*P bf16 (6.4 MB)
    unsigned short* A1k = y2  + (size_t)N_*C_*P_;            // 768*1728 bf16 (2.65 MB)
    unsigned short* A1t = A1k + (size_t)MP_*KK_;             // 64*1728 bf16
    unsigned short* A2t = A1t + (size_t)C_*KK_;              // 64*1728 bf16
    // part2 [784][128] reuses off2's space (off2 dead after deform_fused)
    float* part2 = (float*)off2;

    // prep
    transpose_xt_kernel<<<N_*(P_/64), 256, 0, stream>>>(x, xt);
    permA1k_kernel<<<(MP_*KK_+255)/256, 256, 0, stream>>>(w_off, A1k);
    perm_w_kernel<<<(C_*KK_+255)/256, 256, 0, stream>>>(w1, A1t);
    perm_w_kernel<<<(C_*KK_+255)/256, 256, 0, stream>>>(w2, A2t);

    // conv_off fused -> off2 (both n): main 128x256 tiles + tail MERGED
    conv_off_fused<<<2*490 + 2*196, 256, 0, stream>>>(A1k, xt, b_off, off2);

    // deform fused -> y1t (both n), single-barrier dbuf pipeline
    deform_fused<<<N_*(P_/32), 256, 0, stream>>>(xt, off2, A1t, y1t);

    // BN1 scale/shift
    stats_partial_kernel<<<98, 256, 0, stream>>>(y1t, part);
    stats_final_kernel<<<1, 64, 0, stream>>>(part, g1, be1, st1);

    // conv2 fused (BN1+ReLU on read) -> y2 + BN2 partials
    conv2_fused<<<N_*(P_/64), 256, 0, stream>>>(y1t, st1, A2t, b2, y2, part2);

    // BN2 finalize + apply + residual + ReLU -> out (fp32)
    bn2_final_kernel<<<1, 256, 0, stream>>>(part2, g2, be2, st2);
    bn_add_relu_kernel<<<(N_*C_*P_)/1024, 256, 0, stream>>>(y2, x, st2, out);
}

// Round 9
// 453.740 us; speedup vs baseline: 1.1459x; 1.0292x over previous
//
#include <hip/hip_runtime.h>
#include <hip/hip_bf16.h>

#define N_ 2
#define C_ 64
#define D_ 8
#define H_ 56
#define W_ 56
#define HW_ (H_*W_)        // 3136
#define P_ (D_*HW_)        // 25088
#define G_ 8
#define CPG_ 8
#define K_ 27
#define CO_OFF_ 648        // G * 3 * K
#define MP_ 768            // conv_off M padded (rows 648+ zero)
#define KK_ 1728           // GEMM K dim (= 27*64, k-major: ktap*64 + ci)
#define KB_ (KK_*2)        // bytes per bf16 row

typedef __attribute__((ext_vector_type(8))) short shortx8;
typedef __attribute__((ext_vector_type(4))) float floatx4;
#define AS1 __attribute__((address_space(1)))
#define AS3 __attribute__((address_space(3)))

__device__ inline float b2f(unsigned short u) {
    union { unsigned u; float f; } x; x.u = ((unsigned)u) << 16; return x.f;
}
__device__ inline unsigned short f2b(float f) {
    union { float f; unsigned u; } x; x.f = f;
    unsigned r = (x.u + 0x7fffu + ((x.u >> 16) & 1u)) >> 16;   // RNE
    return (unsigned short)r;
}
__device__ inline float lof(unsigned u) { union { unsigned u; float f; } x; x.u = u << 16; return x.f; }
__device__ inline float hif(unsigned u) { union { unsigned u; float f; } x; x.u = u & 0xffff0000u; return x.f; }
// HW packed f32->bf16 (RNE), 1 inst for 2 values.
__device__ inline unsigned cvt_pk_bf16(float a, float b) {
    unsigned r;
    asm("v_cvt_pk_bf16_f32 %0, %1, %2" : "=v"(r) : "v"(a), "v"(b));
    return r;
}

// off layout: off2[(g*27+kt)*P + p][3] bf16 (interleaved comps, 65 MB total)

// ---------------------------------------------------------------------------
// MERGED prep: transpose_xt (blocks 0..783) | permA1k (784..5967) |
// perm_w w1 (5968..6399) | perm_w w2 (6400..6831). All independent; one
// launch removes 3 serialization gaps.
// ---------------------------------------------------------------------------
__global__ __launch_bounds__(256) void prep_kernel(
    const float* __restrict__ x,      unsigned short* __restrict__ xt,
    const float* __restrict__ w_off,  unsigned short* __restrict__ A1k,
    const float* __restrict__ w1,     unsigned short* __restrict__ A1t,
    const float* __restrict__ w2,     unsigned short* __restrict__ A2t)
{
    __shared__ unsigned short tile[64][65];
    int b   = blockIdx.x;
    int tid = threadIdx.x;

    if (b < 784) {
        // ---- transpose_xt: x [N][64][P] fp32 -> xt [N][P][64] bf16 ----
        int n  = b / (P_/64);
        int p0 = (b % (P_/64))*64;
        int j  = tid & 63;
        int c0 = (tid >> 6)*16;
        for (int r = 0; r < 16; ++r)
            tile[c0 + r][j] = f2b(x[((size_t)n*C_ + c0 + r)*P_ + p0 + j]);
        __syncthreads();
        unsigned* dst = (unsigned*)(xt + ((size_t)n*P_ + p0)*C_);
        #pragma unroll
        for (int it = 0; it < 8; ++it) {
            int wi  = it*256 + tid;
            int row = wi >> 5;
            int c   = (wi & 31)*2;
            unsigned lo = tile[c][row], hi = tile[c+1][row];
            dst[(size_t)row*32 + (wi & 31)] = lo | (hi << 16);
        }
    } else if (b < 784 + 5184) {
        // ---- permA1k: w_off [648][64][27] -> A1k [768][1728] k-major ----
        int i = (b - 784)*256 + tid;     // exact: 5184*256 = 768*1728
        int m = i / KK_, r = i % KK_;
        int kk = r / 64, ci = r % 64;
        A1k[i] = (m < CO_OFF_) ? f2b(w_off[((size_t)m*C_ + ci)*K_ + kk]) : (unsigned short)0;
    } else if (b < 784 + 5184 + 432) {
        // ---- perm_w: w1 -> A1t ----
        int i = (b - 784 - 5184)*256 + tid;  // exact: 432*256 = 64*1728
        int o = i / KK_, r = i % KK_;
        int k = r / 64, ii = r % 64;
        A1t[i] = f2b(w1[((size_t)o*C_ + ii)*K_ + k]);
    } else {
        // ---- perm_w: w2 -> A2t ----
        int i = (b - 784 - 5184 - 432)*256 + tid;
        int o = i / KK_, r = i % KK_;
        int k = r / 64, ii = r % 64;
        A2t[i] = f2b(w2[((size_t)o*C_ + ii)*K_ + k]);
    }
}

// ---------------------------------------------------------------------------
// conv_off fused v3 (R8): MERGED main (128m x 256p, blocks 0..979) + tail
// (rows 640..647, blocks 980..1371) in ONE launch.
// ---------------------------------------------------------------------------
__global__ __launch_bounds__(256, 2) void conv_off_fused(
    const unsigned short* __restrict__ A,    // A1k [768][1728]
    const unsigned short* __restrict__ xt,   // [N][P][64] bf16
    const float* __restrict__ bias,          // [648]
    unsigned short* __restrict__ off2)       // [N][216*P][3] bf16
{
    __shared__ __align__(16) short SH[35840];
    int tid = threadIdx.x;
    int w = tid >> 6, lane = tid & 63;
    int lm = lane & 15, lq = lane >> 4;

    if (blockIdx.x < 2*490) {
        short* As0 = SH;
        short* Bs  = SH + 2*16*512;
        int n   = blockIdx.x / 490;
        int bid = blockIdx.x % 490;
        int mt = bid / 98, nt = bid % 98;
        int m0 = mt*128, p0 = nt*256;

        const unsigned short* xtn = xt + (size_t)n*P_*C_;
        unsigned short* out2 = off2 + (size_t)n*216*P_*3;

        const char* Ab0 = (const char*)A + (size_t)(m0 + w*32 + lm)*KB_ + lq*16;
        const char* Ab1 = Ab0 + (size_t)16*KB_;

        int oct = lane & 7;
        int prj[8], dj[8], hj[8], wj[8];
        #pragma unroll
        for (int j = 0; j < 8; ++j) {
            int prow = j*32 + w*8 + (lane >> 3);
            prj[j] = prow;
            int p = p0 + prow;
            dj[j] = p / HW_;
            int hw2 = p % HW_;
            hj[j] = hw2 / W_;
            wj[j] = hw2 % W_;
        }

        auto stageA = [&](int kt, int buf) {
            __builtin_amdgcn_global_load_lds((const AS1 unsigned*)(Ab0 + kt*128),      (AS3 unsigned*)(As0 + buf*8192 + (w*2)*512),     16, 0, 0);
            __builtin_amdgcn_global_load_lds((const AS1 unsigned*)(Ab1 + kt*128),      (AS3 unsigned*)(As0 + buf*8192 + (w*2+1)*512),   16, 0, 0);
            __builtin_amdgcn_global_load_lds((const AS1 unsigned*)(Ab0 + kt*128 + 64), (AS3 unsigned*)(As0 + buf*8192 + (8+w*2)*512),   16, 0, 0);
            __builtin_amdgcn_global_load_lds((const AS1 unsigned*)(Ab1 + kt*128 + 64), (AS3 unsigned*)(As0 + buf*8192 + (8+w*2+1)*512), 16, 0, 0);
        };
        auto loadB = [&](int kt, uint4* B) {
            int kd = kt/9 - 1, kh = (kt/3)%3 - 1, kw = kt%3 - 1;
            int delta = kd*HW_ + kh*W_ + kw;
            #pragma unroll
            for (int j = 0; j < 8; ++j) {
                bool v = ((unsigned)(dj[j]+kd) < (unsigned)D_) &&
                         ((unsigned)(hj[j]+kh) < (unsigned)H_) &&
                         ((unsigned)(wj[j]+kw) < (unsigned)W_);
                uint4 val = {0u,0u,0u,0u};
                if (v) val = *(const uint4*)(xtn + (size_t)(p0 + prj[j] + delta)*C_ + oct*8);
                B[j] = val;
            }
        };

        int mh = w >> 1, nh = w & 1;
        floatx4 acc[4][8];
        #pragma unroll
        for (int i = 0; i < 4; ++i)
            #pragma unroll
            for (int j = 0; j < 8; ++j)
                acc[i][j] = (floatx4){0.f, 0.f, 0.f, 0.f};

        uint4 Bcur[8], Bnext[8];
        #pragma unroll
        for (int j = 0; j < 8; ++j) Bnext[j] = (uint4){0u,0u,0u,0u};
        stageA(0, 0);
        loadB(0, Bcur);

        for (int kt = 0; kt < 27; ++kt) {
            int buf = kt & 1;
            __syncthreads();
            #pragma unroll
            for (int j = 0; j < 8; ++j) {
                int chunk = (oct>>2)*16 + (prj[j]>>4);
                *(uint4*)&Bs[chunk*512 + ((oct&3)*16 + ((prj[j]&15) ^ oct))*8] = Bcur[j];
            }
            __syncthreads();
            if (kt < 26) { stageA(kt+1, buf^1); loadB(kt+1, Bnext); }
            #pragma unroll
            for (int ks = 0; ks < 2; ++ks) {
                int swzB = (lq*16 + (lm ^ (ks*4 + lq)))*8;
                shortx8 a[4];
                #pragma unroll
                for (int i = 0; i < 4; ++i) a[i] = *(const shortx8*)&As0[buf*8192 + (ks*8 + 4*mh + i)*512 + lane*8];
                #pragma unroll
                for (int j = 0; j < 8; ++j) {
                    shortx8 b = *(const shortx8*)&Bs[(ks*16 + 8*nh + j)*512 + swzB];
                    #pragma unroll
                    for (int i = 0; i < 4; ++i)
                        acc[i][j] = __builtin_amdgcn_mfma_f32_16x16x32_bf16(a[i], b, acc[i][j], 0, 0, 0);
                }
            }
            #pragma unroll
            for (int j = 0; j < 8; ++j) Bcur[j] = Bnext[j];
        }

        #pragma unroll
        for (int i = 0; i < 4; ++i) {
            int cob = m0 + (4*mh+i)*16 + lq*4;
            #pragma unroll
            for (int r = 0; r < 4; ++r) {
                int co = cob + r;    // < 640 always (mt <= 4)
                float bv = bias[co];
                int row2 = co / 3, comp = co % 3;
                size_t base = (size_t)row2*P_*3 + comp;
                #pragma unroll
                for (int j = 0; j < 8; ++j) {
                    int col = p0 + (8*nh+j)*16 + lm;
                    out2[base + (size_t)col*3] = f2b(acc[i][j][r] + bv);
                }
            }
        }
    } else {
        short* As = SH;
        short* Bs = SH + 54*512;
        int t  = blockIdx.x - 2*490;
        int n  = t / 196;
        int p0 = (t % 196)*128;

        const unsigned short* xtn = xt + (size_t)n*P_*C_;
        unsigned short* out2 = off2 + (size_t)n*216*P_*3;

        const char* Abase = (const char*)A + (size_t)(640 + lm)*KB_ + lq*16;
        for (int ch = w; ch < 54; ch += 4)
            __builtin_amdgcn_global_load_lds((const AS1 unsigned*)(Abase + ch*64),
                                             (AS3 unsigned*)(As + ch*512), 16, 0, 0);

        int oct = lane & 7;
        int prj[4], dj[4], hj[4], wj[4];
        #pragma unroll
        for (int j = 0; j < 4; ++j) {
            int prow = j*32 + w*8 + (lane >> 3);
            prj[j] = prow;
            int p = p0 + prow;
            dj[j] = p / HW_;
            int hw2 = p % HW_;
            hj[j] = hw2 / W_;
            wj[j] = hw2 % W_;
        }
        auto loadB = [&](int kt, uint4* B) {
            int kd = kt/9 - 1, kh = (kt/3)%3 - 1, kw = kt%3 - 1;
            int delta = kd*HW_ + kh*W_ + kw;
            #pragma unroll
            for (int j = 0; j < 4; ++j) {
                bool v = ((unsigned)(dj[j]+kd) < (unsigned)D_) &&
                         ((unsigned)(hj[j]+kh) < (unsigned)H_) &&
                         ((unsigned)(wj[j]+kw) < (unsigned)W_);
                uint4 val = {0u,0u,0u,0u};
                if (v) val = *(const uint4*)(xtn + (size_t)(p0 + prj[j] + delta)*C_ + oct*8);
                B[j] = val;
            }
        };

        floatx4 acc[2];
        acc[0] = (floatx4){0.f,0.f,0.f,0.f};
        acc[1] = (floatx4){0.f,0.f,0.f,0.f};

        uint4 Bcur[4], Bnext[4];
        #pragma unroll
        for (int j = 0; j < 4; ++j) Bnext[j] = (uint4){0u,0u,0u,0u};
        loadB(0, Bcur);

        for (int kt = 0; kt < 27; ++kt) {
            __syncthreads();
            #pragma unroll
            for (int j = 0; j < 4; ++j) {
                int chunk = (oct>>2)*8 + (prj[j]>>4);
                *(uint4*)&Bs[chunk*512 + ((oct&3)*16 + ((prj[j]&15) ^ oct))*8] = Bcur[j];
            }
            __syncthreads();
            if (kt < 26) loadB(kt+1, Bnext);
            #pragma unroll
            for (int ks = 0; ks < 2; ++ks) {
                int swzB = (lq*16 + (lm ^ (ks*4 + lq)))*8;
                shortx8 a = *(const shortx8*)&As[(kt*2 + ks)*512 + lane*8];
                #pragma unroll
                for (int j = 0; j < 2; ++j) {
                    shortx8 b = *(const shortx8*)&Bs[(ks*8 + w*2 + j)*512 + swzB];
                    acc[j] = __builtin_amdgcn_mfma_f32_16x16x32_bf16(a, b, acc[j], 0, 0, 0);
                }
            }
            #pragma unroll
            for (int j = 0; j < 4; ++j) Bcur[j] = Bnext[j];
        }

        #pragma unroll
        for (int j = 0; j < 2; ++j) {
            #pragma unroll
            for (int r = 0; r < 4; ++r) {
                int co = 640 + lq*4 + r;
                if (co < CO_OFF_) {
                    int col = p0 + w*32 + j*16 + lm;
                    out2[((size_t)(co/3)*P_ + col)*3 + (co%3)] = f2b(acc[j][r] + bias[co]);
                }
            }
        }
    }
}

// ---------------------------------------------------------------------------
// deform fused (R6 loop, UNTOUCHED) + BN1 partial sums fused in epilogue
// (reads the y1 tile already in LDS; removes the stats_partial pass).
// ---------------------------------------------------------------------------
__global__ __launch_bounds__(256) void deform_fused(
    const unsigned short* __restrict__ xt,   // [N][P][64] bf16
    const unsigned short* __restrict__ off2, // [N][216*P][3] bf16
    const unsigned short* __restrict__ A,    // A1t [64][1728]
    unsigned short* __restrict__ y1t,        // [N][P][64] bf16
    float* __restrict__ bn1p)                // [1568][128] block partials
{
    __shared__ __align__(16) short SH[12288]; // A dbuf 2x4096, B dbuf 2x2048
    int tid = threadIdx.x;
    int w = tid >> 6, lane = tid & 63;
    int n  = blockIdx.x / (P_/32);
    int p0 = (blockIdx.x % (P_/32))*32;
    int lm = lane & 15, lq = lane >> 4;

    const unsigned short* offn = off2 + (size_t)n*216*P_*3;
    const uint4* xg0 = (const uint4*)(xt + (size_t)n*P_*C_);

    const char* Ab = (const char*)A + (size_t)(w*16 + lm)*KB_ + lq*16;

    int g = lane & 7;
    int prow = tid >> 3;          // 0..31
    int p = p0 + prow;
    int dd = p / HW_;
    int hw2 = p % HW_;
    int hh = hw2 / W_;
    int ww = hw2 % W_;
    int bchunk = (g>>2)*2 + (prow>>4);
    int boffs  = ((g&3)*16 + ((prow&15) ^ g))*8;

    auto stageA = [&](int kt, int buf) {
        __builtin_amdgcn_global_load_lds((const AS1 unsigned*)(Ab + kt*128),      (AS3 unsigned*)(SH + buf*4096 + w*512),     16, 0, 0);
        __builtin_amdgcn_global_load_lds((const AS1 unsigned*)(Ab + kt*128 + 64), (AS3 unsigned*)(SH + buf*4096 + (4+w)*512), 16, 0, 0);
    };
    auto loadOff = [&](int kt, float* o) {
        size_t idx = ((size_t)(g*K_ + kt)*P_ + p)*3;
        o[0] = b2f(offn[idx]);
        o[1] = b2f(offn[idx + 1]);
        o[2] = b2f(offn[idx + 2]);
    };
    auto issueCorners = [&](int kt, float* o, uint4* V, float* Wt) {
        int kd = kt/9 - 1, kh = (kt/3)%3 - 1, kw = kt%3 - 1;
        float pd = (float)(dd + kd) + o[0];
        float ph = (float)(hh + kh) + o[1];
        float pw = (float)(ww + kw) + o[2];
        float fd0 = floorf(pd), fh0 = floorf(ph), fw0 = floorf(pw);
        int d0 = (int)fd0, h0 = (int)fh0, w0i = (int)fw0;
        float fd = pd - fd0, fh = ph - fh0, fw = pw - fw0;
        int dc0 = min(max(d0, 0), D_-1),   dc1 = min(max(d0+1, 0), D_-1);
        int hc0 = min(max(h0, 0), H_-1),   hc1 = min(max(h0+1, 0), H_-1);
        int wc0 = min(max(w0i, 0), W_-1),  wc1 = min(max(w0i+1, 0), W_-1);
        float wd0 = ((unsigned)d0      < (unsigned)D_) ? 1.f - fd : 0.f;
        float wd1 = ((unsigned)(d0+1)  < (unsigned)D_) ? fd       : 0.f;
        float wh0 = ((unsigned)h0      < (unsigned)H_) ? 1.f - fh : 0.f;
        float wh1 = ((unsigned)(h0+1)  < (unsigned)H_) ? fh       : 0.f;
        float ww0 = ((unsigned)w0i     < (unsigned)W_) ? 1.f - fw : 0.f;
        float ww1 = ((unsigned)(w0i+1) < (unsigned)W_) ? fw       : 0.f;
        int rb00 = (dc0*H_ + hc0)*W_, rb01 = (dc0*H_ + hc1)*W_;
        int rb10 = (dc1*H_ + hc0)*W_, rb11 = (dc1*H_ + hc1)*W_;
        float wdh00 = wd0*wh0, wdh01 = wd0*wh1, wdh10 = wd1*wh0, wdh11 = wd1*wh1;
        V[0] = xg0[(size_t)(rb00+wc0)*8 + g];  Wt[0] = wdh00*ww0;
        V[1] = xg0[(size_t)(rb00+wc1)*8 + g];  Wt[1] = wdh00*ww1;
        V[2] = xg0[(size_t)(rb01+wc0)*8 + g];  Wt[2] = wdh01*ww0;
        V[3] = xg0[(size_t)(rb01+wc1)*8 + g];  Wt[3] = wdh01*ww1;
        V[4] = xg0[(size_t)(rb10+wc0)*8 + g];  Wt[4] = wdh10*ww0;
        V[5] = xg0[(size_t)(rb10+wc1)*8 + g];  Wt[5] = wdh10*ww1;
        V[6] = xg0[(size_t)(rb11+wc0)*8 + g];  Wt[6] = wdh11*ww0;
        V[7] = xg0[(size_t)(rb11+wc1)*8 + g];  Wt[7] = wdh11*ww1;
    };
    auto reduceCorners = [&](uint4* V, float* Wt, uint4& o4) {
        float res[CPG_];
        #pragma unroll
        for (int c = 0; c < CPG_; ++c) res[c] = 0.f;
        #pragma unroll
        for (int c = 0; c < 8; ++c) {
            uint4 v4 = V[c];
            float wgt = Wt[c];
            res[0] = fmaf(wgt, lof(v4.x), res[0]);
            res[1] = fmaf(wgt, hif(v4.x), res[1]);
            res[2] = fmaf(wgt, lof(v4.y), res[2]);
            res[3] = fmaf(wgt, hif(v4.y), res[3]);
            res[4] = fmaf(wgt, lof(v4.z), res[4]);
            res[5] = fmaf(wgt, hif(v4.z), res[5]);
            res[6] = fmaf(wgt, lof(v4.w), res[6]);
            res[7] = fmaf(wgt, hif(v4.w), res[7]);
        }
        o4.x = cvt_pk_bf16(res[0], res[1]);
        o4.y = cvt_pk_bf16(res[2], res[3]);
        o4.z = cvt_pk_bf16(res[4], res[5]);
        o4.w = cvt_pk_bf16(res[6], res[7]);
    };

    int mh = w >> 1, nh = w & 1;
    floatx4 acc[2];
    acc[0] = (floatx4){0.f,0.f,0.f,0.f};
    acc[1] = (floatx4){0.f,0.f,0.f,0.f};

    float offA[3], offB[3], offT[3];
    uint4 Vv[8]; float Wt[8];
    uint4 o4cur;

    stageA(0, 0);
    loadOff(0, offA);
    loadOff(1, offB);
    issueCorners(0, offA, Vv, Wt);
    reduceCorners(Vv, Wt, o4cur);
    *(uint4*)&SH[8192 + bchunk*512 + boffs] = o4cur;   // B(0) -> Bs buf 0

    for (int kt = 0; kt < 27; ++kt) {
        int buf = kt & 1;
        __syncthreads();   // Bs[buf] writes + As[buf] staging drained
        if (kt < 26) {
            stageA(kt+1, buf^1);
            if (kt < 25) loadOff(kt+2, offT);
            issueCorners(kt+1, offB, Vv, Wt);
        }
        #pragma unroll
        for (int ks = 0; ks < 2; ++ks) {
            int swzB = (lq*16 + (lm ^ (ks*4 + lq)))*8;
            shortx8 b = *(const shortx8*)&SH[8192 + buf*2048 + (ks*2 + nh)*512 + swzB];
            #pragma unroll
            for (int i = 0; i < 2; ++i) {
                shortx8 a = *(const shortx8*)&SH[buf*4096 + (ks*4 + 2*mh+i)*512 + lane*8];
                acc[i] = __builtin_amdgcn_mfma_f32_16x16x32_bf16(a, b, acc[i], 0, 0, 0);
            }
        }
        if (kt < 26) {
            reduceCorners(Vv, Wt, o4cur);
            *(uint4*)&SH[8192 + (buf^1)*2048 + bchunk*512 + boffs] = o4cur;
            offB[0] = offT[0]; offB[1] = offT[1]; offB[2] = offT[2];
        }
    }

    // epilogue: transpose 64o x 32p tile to y1t[p][o] via LDS (stride 72)
    __syncthreads();
    #pragma unroll
    for (int i = 0; i < 2; ++i) {
        int ob = mh*32 + i*16 + lq*4;
        int pc = nh*16 + lm;
        #pragma unroll
        for (int rr = 0; rr < 4; ++rr)
            SH[pc*72 + ob + rr] = (short)f2b(acc[i][rr]);
    }
    __syncthreads();
    {
        int row = tid >> 3, seg = tid & 7;
        uint4 v = *(const uint4*)&SH[row*72 + seg*8];
        *(uint4*)(y1t + ((size_t)n*P_ + p0 + row)*C_ + seg*8) = v;
    }
    // BN1 partials from the y1 tile in LDS (SHT = SH[0..2304), bf16)
    {
        float* FS = (float*)(SH + 2560);   // 256 floats
        float* FQ = FS + 256;              // 256 floats (ends at byte 7168)
        int o = tid & 63, qt = tid >> 6;
        float s = 0.f, q = 0.f;
        #pragma unroll
        for (int pp = 0; pp < 8; ++pp) {
            float v = b2f((unsigned short)SH[(qt*8 + pp)*72 + o]);
            s += v;
            q = fmaf(v, v, q);
        }
        FS[qt*64 + o] = s;
        FQ[qt*64 + o] = q;
        __syncthreads();
        if (tid < 64) {
            float S = FS[tid] + FS[64+tid] + FS[128+tid] + FS[192+tid];
            float Q = FQ[tid] + FQ[64+tid] + FQ[128+tid] + FQ[192+tid];
            bn1p[(size_t)blockIdx.x*128 + tid]      = S;
            bn1p[(size_t)blockIdx.x*128 + 64 + tid] = Q;
        }
    }
}

// ---------------------------------------------------------------------------
// conv2 fused v5: 64o x 128p blocks (2 p-groups/wave -> 16 MFMA/tap/wave,
// halves barrier frequency per MFMA — R6's proven lever). Quad-buffer As,
// BN2 partials in epilogue. Grid 392.
// ---------------------------------------------------------------------------
__global__ __launch_bounds__(256) void conv2_fused(
    const unsigned short* __restrict__ y1t,  // [N][P][64] bf16
    const float* __restrict__ st1,           // [64] scale, [64] shift
    const unsigned short* __restrict__ A,    // A2t [64][1728]
    const float* __restrict__ bias,          // [64]
    unsigned short* __restrict__ y2,         // [N][64][P] bf16
    float* __restrict__ part2)               // [392][128] block partials
{
    __shared__ __align__(16) short As[4][4096];   // 32 KB quad-buffer
    __shared__ float sc[64], sf[64];
    __shared__ float SP[4][64], SQ[4][64];
    int tid = threadIdx.x;
    if (tid < 64) sc[tid] = st1[tid];
    else if (tid < 128) sf[tid-64] = st1[tid];
    int w = tid >> 6, lane = tid & 63;
    int n  = blockIdx.x / (P_/128);
    int p0 = (blockIdx.x % (P_/128))*128;
    int lm = lane & 15, lq = lane >> 4;

    const unsigned short* y1n = y1t + (size_t)n*P_*C_;
    unsigned short* y2n = y2 + (size_t)n*C_*P_;
    const char* Ab = (const char*)A + (size_t)(w*16 + lm)*KB_ + lq*16;

    int pj[2], dd[2], hh[2], ww[2];
    #pragma unroll
    for (int j = 0; j < 2; ++j) {
        pj[j] = p0 + j*64 + w*16 + lm;
        dd[j] = pj[j] / HW_;
        int hw2 = pj[j] % HW_;
        hh[j] = hw2 / W_;
        ww[j] = hw2 % W_;
    }

    auto stageA = [&](int kt) {
        int buf = kt & 3;
        __builtin_amdgcn_global_load_lds((const AS1 unsigned*)(Ab + kt*128),      (AS3 unsigned*)(&As[buf][w*512]),     16, 0, 0);
        __builtin_amdgcn_global_load_lds((const AS1 unsigned*)(Ab + kt*128 + 64), (AS3 unsigned*)(&As[buf][(4+w)*512]), 16, 0, 0);
    };
    // V[j][ks], M[j]
    auto issueV = [&](int kt, uint4 (*V)[2], int* M) {
        int kd = kt/9 - 1, kh = (kt/3)%3 - 1, kw = kt%3 - 1;
        int delta = kd*HW_ + kh*W_ + kw;
        #pragma unroll
        for (int j = 0; j < 2; ++j) {
            bool v = ((unsigned)(dd[j]+kd) < (unsigned)D_) &&
                     ((unsigned)(hh[j]+kh) < (unsigned)H_) &&
                     ((unsigned)(ww[j]+kw) < (unsigned)W_);
            M[j] = v ? 1 : 0;
            #pragma unroll
            for (int ks = 0; ks < 2; ++ks) {
                uint4 val = {0u,0u,0u,0u};
                if (v) val = *(const uint4*)(y1n + (size_t)(pj[j] + delta)*C_ + (ks*4 + lq)*8);
                V[j][ks] = val;
            }
        }
    };
    auto reduceT = [&](uint4 V, int ks, int M) -> shortx8 {
        uint4 o4 = {0u,0u,0u,0u};
        if (M) {
            int cb = (ks*4 + lq)*8;
            float r0 = fmaxf(lof(V.x)*sc[cb+0] + sf[cb+0], 0.f);
            float r1 = fmaxf(hif(V.x)*sc[cb+1] + sf[cb+1], 0.f);
            float r2 = fmaxf(lof(V.y)*sc[cb+2] + sf[cb+2], 0.f);
            float r3 = fmaxf(hif(V.y)*sc[cb+3] + sf[cb+3], 0.f);
            float r4 = fmaxf(lof(V.z)*sc[cb+4] + sf[cb+4], 0.f);
            float r5 = fmaxf(hif(V.z)*sc[cb+5] + sf[cb+5], 0.f);
            float r6 = fmaxf(lof(V.w)*sc[cb+6] + sf[cb+6], 0.f);
            float r7 = fmaxf(hif(V.w)*sc[cb+7] + sf[cb+7], 0.f);
            o4.x = cvt_pk_bf16(r0, r1);
            o4.y = cvt_pk_bf16(r2, r3);
            o4.z = cvt_pk_bf16(r4, r5);
            o4.w = cvt_pk_bf16(r6, r7);
        }
        return *(shortx8*)&o4;
    };

    floatx4 acc[4][2];
    #pragma unroll
    for (int i = 0; i < 4; ++i)
        #pragma unroll
        for (int j = 0; j < 2; ++j)
            acc[i][j] = (floatx4){0.f,0.f,0.f,0.f};

    auto mfmaTap = [&](int kt, uint4 (*V)[2], const int* M) {
        int buf = kt & 3;
        #pragma unroll
        for (int j = 0; j < 2; ++j) {
            shortx8 b0 = reduceT(V[j][0], 0, M[j]);
            shortx8 b1 = reduceT(V[j][1], 1, M[j]);
            #pragma unroll
            for (int i = 0; i < 4; ++i) {
                shortx8 a = *(const shortx8*)&As[buf][(0*4 + i)*512 + lane*8];
                acc[i][j] = __builtin_amdgcn_mfma_f32_16x16x32_bf16(a, b0, acc[i][j], 0, 0, 0);
            }
            #pragma unroll
            for (int i = 0; i < 4; ++i) {
                shortx8 a = *(const shortx8*)&As[buf][(1*4 + i)*512 + lane*8];
                acc[i][j] = __builtin_amdgcn_mfma_f32_16x16x32_bf16(a, b1, acc[i][j], 0, 0, 0);
            }
        }
    };

    uint4 VA[2][2], VB[2][2];
    int MA[2], MB[2];
    stageA(0); stageA(1);
    issueV(0, VA, MA);
    issueV(1, VB, MB);

    for (int kt = 0; kt < 26; kt += 2) {
        __syncthreads();
        stageA(kt+2);
        if (kt+3 <= 26) stageA(kt+3);
        {
            uint4 Vc[2][2];
            #pragma unroll
            for (int j = 0; j < 2; ++j) { Vc[j][0] = VA[j][0]; Vc[j][1] = VA[j][1]; }
            int Mc[2] = {MA[0], MA[1]};
            issueV(kt+2, VA, MA);
            mfmaTap(kt, Vc, Mc);
        }
        {
            uint4 Vc[2][2];
            #pragma unroll
            for (int j = 0; j < 2; ++j) { Vc[j][0] = VB[j][0]; Vc[j][1] = VB[j][1]; }
            int Mc[2] = {MB[0], MB[1]};
            if (kt+3 <= 26) issueV(kt+3, VB, MB);
            mfmaTap(kt+1, Vc, Mc);
        }
    }
    __syncthreads();
    mfmaTap(26, VA, MA);

    // epilogue: y2 write + BN2 partials (128 p per block)
    #pragma unroll
    for (int i = 0; i < 4; ++i) {
        #pragma unroll
        for (int r = 0; r < 4; ++r) {
            int co = i*16 + lq*4 + r;
            float v0 = acc[i][0][r] + bias[co];
            float v1 = acc[i][1][r] + bias[co];
            y2n[(size_t)co*P_ + pj[0]] = f2b(v0);
            y2n[(size_t)co*P_ + pj[1]] = f2b(v1);
            float s = v0 + v1;
            float q = v0*v0 + v1*v1;
            #pragma unroll
            for (int m = 1; m < 16; m <<= 1) {
                s += __shfl_xor(s, m);
                q += __shfl_xor(q, m);
            }
            if (lm == 0) { SP[w][co] = s; SQ[w][co] = q; }
        }
    }
    __syncthreads();
    if (tid < 64) {
        float S = SP[0][tid] + SP[1][tid] + SP[2][tid] + SP[3][tid];
        float Q = SQ[0][tid] + SQ[1][tid] + SQ[2][tid] + SQ[3][tid];
        part2[(size_t)blockIdx.x*128 + tid]      = S;
        part2[(size_t)blockIdx.x*128 + 64 + tid] = Q;
    }
}

// ---------------------------------------------------------------------------
// BN1 finalize from deform partials (1568 blocks) -> st1 (scale, shift)
// ---------------------------------------------------------------------------
__global__ __launch_bounds__(256) void stats_final_kernel(
    const float* __restrict__ part,
    const float* __restrict__ gamma, const float* __restrict__ beta,
    float* __restrict__ st1)
{
    int tid = threadIdx.x;
    int c = tid & 63, seg = tid >> 6;
    float S = 0.f, Q = 0.f;
    for (int b = seg*392; b < seg*392 + 392; ++b) {
        S += part[(size_t)b*128 + c];
        Q += part[(size_t)b*128 + 64 + c];
    }
    __shared__ float ss[256], qq[256];
    ss[tid] = S; qq[tid] = Q;
    __syncthreads();
    if (tid < 64) {
        float St = ss[tid] + ss[64+tid] + ss[128+tid] + ss[192+tid];
        float Qt = qq[tid] + qq[64+tid] + qq[128+tid] + qq[192+tid];
        const float inv = 1.f / (float)(N_*P_);
        float m = St * inv;
        float var = Qt * inv - m*m;
        float scale = rsqrtf(var + 1e-5f) * gamma[tid];
        st1[tid]      = scale;
        st1[64 + tid] = beta[tid] - m*scale;
    }
}

// ---------------------------------------------------------------------------
// BN2 finalize from conv2 partials (392 blocks) -> st2 (scale, shift)
// ---------------------------------------------------------------------------
__global__ __launch_bounds__(256) void bn2_final_kernel(
    const float* __restrict__ part2,
    const float* __restrict__ gamma, const float* __restrict__ beta,
    float* __restrict__ st2)
{
    int tid = threadIdx.x;
    int c = tid & 63, seg = tid >> 6;
    float S = 0.f, Q = 0.f;
    for (int b = seg*98; b < seg*98 + 98; ++b) {
        S += part2[(size_t)b*128 + c];
        Q += part2[(size_t)b*128 + 64 + c];
    }
    __shared__ float ss[256], qq[256];
    ss[tid] = S; qq[tid] = Q;
    __syncthreads();
    if (tid < 64) {
        float St = ss[tid] + ss[64+tid] + ss[128+tid] + ss[192+tid];
        float Qt = qq[tid] + qq[64+tid] + qq[128+tid] + qq[192+tid];
        const float inv = 1.f / (float)(N_*P_);
        float m = St * inv;
        float var = Qt * inv - m*m;
        float scale = rsqrtf(var + 1e-5f) * gamma[tid];
        st2[tid]      = scale;
        st2[64 + tid] = beta[tid] - m*scale;
    }
}

// ---------------------------------------------------------------------------
// BN2 apply + residual + ReLU, vectorized x4 (uint2 y2 / float4 x,out)
// ---------------------------------------------------------------------------
__global__ __launch_bounds__(256) void bn_add_relu_kernel(
    const unsigned short* __restrict__ y2, const float* __restrict__ x,
    const float* __restrict__ st2, float* __restrict__ out)
{
    size_t i4 = ((size_t)blockIdx.x*256 + threadIdx.x)*4;
    int c = (int)((i4 / P_) % C_);
    float scale = st2[c], shift = st2[64 + c];
    uint2 yv = *(const uint2*)(y2 + i4);
    float4 xv = *(const float4*)(x + i4);
    float4 o;
    o.x = fmaxf(fmaf(lof(yv.x), scale, shift) + xv.x, 0.f);
    o.y = fmaxf(fmaf(hif(yv.x), scale, shift) + xv.y, 0.f);
    o.z = fmaxf(fmaf(lof(yv.y), scale, shift) + xv.z, 0.f);
    o.w = fmaxf(fmaf(hif(yv.y), scale, shift) + xv.w, 0.f);
    *(float4*)(out + i4) = o;
}

// ---------------------------------------------------------------------------
extern "C" void kernel_launch(void* const* d_in, const int* in_sizes, int n_in,
                              void* d_out, int out_size, void* d_ws, size_t ws_size,
                              hipStream_t stream) {
    const float* x     = (const float*)d_in[0];
    const float* w_off = (const float*)d_in[1];
    const float* b_off = (const float*)d_in[2];
    const float* w1    = (const float*)d_in[3];
    const float* g1    = (const float*)d_in[4];
    const float* be1   = (const float*)d_in[5];
    const float* w2    = (const float*)d_in[6];
    const float* b2    = (const float*)d_in[7];
    const float* g2    = (const float*)d_in[8];
    const float* be2   = (const float*)d_in[9];
    float* out = (float*)d_out;

    // workspace (~89 MB)
    float* st1  = (float*)d_ws;                              // 128 (scale/shift BN1)
    float* st2  = st1 + 128;                                 // 128 (scale/shift BN2)
    float* bn1p = st2 + 128;                                 // 1568*128 (803 KB)
    unsigned short* off2 = (unsigned short*)(bn1p + 1568*128); // N*216*P*3 bf16 (65 MB)
    unsigned short* xt  = off2 + (size_t)N_*216*P_*3;        // N*P*64 bf16 (6.4 MB)
    unsigned short* y1t = xt  + (size_t)N_*P_*C_;            // N*P*64 bf16 (6.4 MB)
    unsigned short* y2  = y1t + (size_t)N_*P_*C_;            // N*64*P bf16 (6.4 MB)
    unsigned short* A1k = y2  + (size_t)N_*C_*P_;            // 768*1728 bf16 (2.65 MB)
    unsigned short* A1t = A1k + (size_t)MP_*KK_;             // 64*1728 bf16
    unsigned short* A2t = A1t + (size_t)C_*KK_;              // 64*1728 bf16
    // part2 [392][128] reuses off2's space (off2 dead after deform_fused)
    float* part2 = (float*)off2;

    // prep: transpose + all weight permutes in ONE launch
    prep_kernel<<<784 + 5184 + 432 + 432, 256, 0, stream>>>(
        x, xt, w_off, A1k, w1, A1t, w2, A2t);

    // conv_off fused -> off2 (both n): main 128x256 tiles + tail MERGED
    conv_off_fused<<<2*490 + 2*196, 256, 0, stream>>>(A1k, xt, b_off, off2);

    // deform fused -> y1t + BN1 partials (both n)
    deform_fused<<<N_*(P_/32), 256, 0, stream>>>(xt, off2, A1t, y1t, bn1p);

    // BN1 finalize
    stats_final_kernel<<<1, 256, 0, stream>>>(bn1p, g1, be1, st1);

    // conv2 fused (BN1+ReLU on read) -> y2 + BN2 partials, 128p blocks
    conv2_fused<<<N_*(P_/128), 256, 0, stream>>>(y1t, st1, A2t, b2, y2, part2);

    // BN2 finalize + apply + residual + ReLU -> out (fp32)
    bn2_final_kernel<<<1, 256, 0, stream>>>(part2, g2, be2, st2);
    bn_add_relu_kernel<<<(N_*C_*P_)/1024, 256, 0, stream>>>(y2, x, st2, out);
}

// Round 10
// 449.937 us; speedup vs baseline: 1.1556x; 1.0085x over previous
//
#include <hip/hip_runtime.h>
#include <hip/hip_bf16.h>

#define N_ 2
#define C_ 64
#define D_ 8
#define H_ 56
#define W_ 56
#define HW_ (H_*W_)        // 3136
#define P_ (D_*HW_)        // 25088
#define G_ 8
#define CPG_ 8
#define K_ 27
#define CO_OFF_ 648        // G * 3 * K
#define MP_ 768            // conv_off M padded (rows 648+ zero)
#define KK_ 1728           // GEMM K dim (= 27*64, k-major: ktap*64 + ci)
#define KB_ (KK_*2)        // bytes per bf16 row

typedef __attribute__((ext_vector_type(8))) short shortx8;
typedef __attribute__((ext_vector_type(4))) float floatx4;
#define AS1 __attribute__((address_space(1)))
#define AS3 __attribute__((address_space(3)))

__device__ inline float b2f(unsigned short u) {
    union { unsigned u; float f; } x; x.u = ((unsigned)u) << 16; return x.f;
}
__device__ inline unsigned short f2b(float f) {
    union { float f; unsigned u; } x; x.f = f;
    unsigned r = (x.u + 0x7fffu + ((x.u >> 16) & 1u)) >> 16;   // RNE
    return (unsigned short)r;
}
__device__ inline float lof(unsigned u) { union { unsigned u; float f; } x; x.u = u << 16; return x.f; }
__device__ inline float hif(unsigned u) { union { unsigned u; float f; } x; x.u = u & 0xffff0000u; return x.f; }
// HW packed f32->bf16 (RNE), 1 inst for 2 values.
__device__ inline unsigned cvt_pk_bf16(float a, float b) {
    unsigned r;
    asm("v_cvt_pk_bf16_f32 %0, %1, %2" : "=v"(r) : "v"(a), "v"(b));
    return r;
}

// off layout: off2[(g*27+kt)*P + p][3] bf16 (interleaved comps, 65 MB total)

// ---------------------------------------------------------------------------
// MERGED prep: transpose_xt (blocks 0..783) | permA1k (784..5967) |
// perm_w w1 (5968..6399) | perm_w w2 (6400..6831).
// ---------------------------------------------------------------------------
__global__ __launch_bounds__(256) void prep_kernel(
    const float* __restrict__ x,      unsigned short* __restrict__ xt,
    const float* __restrict__ w_off,  unsigned short* __restrict__ A1k,
    const float* __restrict__ w1,     unsigned short* __restrict__ A1t,
    const float* __restrict__ w2,     unsigned short* __restrict__ A2t)
{
    __shared__ unsigned short tile[64][65];
    int b   = blockIdx.x;
    int tid = threadIdx.x;

    if (b < 784) {
        int n  = b / (P_/64);
        int p0 = (b % (P_/64))*64;
        int j  = tid & 63;
        int c0 = (tid >> 6)*16;
        for (int r = 0; r < 16; ++r)
            tile[c0 + r][j] = f2b(x[((size_t)n*C_ + c0 + r)*P_ + p0 + j]);
        __syncthreads();
        unsigned* dst = (unsigned*)(xt + ((size_t)n*P_ + p0)*C_);
        #pragma unroll
        for (int it = 0; it < 8; ++it) {
            int wi  = it*256 + tid;
            int row = wi >> 5;
            int c   = (wi & 31)*2;
            unsigned lo = tile[c][row], hi = tile[c+1][row];
            dst[(size_t)row*32 + (wi & 31)] = lo | (hi << 16);
        }
    } else if (b < 784 + 5184) {
        int i = (b - 784)*256 + tid;
        int m = i / KK_, r = i % KK_;
        int kk = r / 64, ci = r % 64;
        A1k[i] = (m < CO_OFF_) ? f2b(w_off[((size_t)m*C_ + ci)*K_ + kk]) : (unsigned short)0;
    } else if (b < 784 + 5184 + 432) {
        int i = (b - 784 - 5184)*256 + tid;
        int o = i / KK_, r = i % KK_;
        int k = r / 64, ii = r % 64;
        A1t[i] = f2b(w1[((size_t)o*C_ + ii)*K_ + k]);
    } else {
        int i = (b - 784 - 5184 - 432)*256 + tid;
        int o = i / KK_, r = i % KK_;
        int k = r / 64, ii = r % 64;
        A2t[i] = f2b(w2[((size_t)o*C_ + ii)*K_ + k]);
    }
}

// ---------------------------------------------------------------------------
// conv_off fused v3 (R8): MERGED main (128m x 256p, blocks 0..979) + tail
// (rows 640..647, blocks 980..1371) in ONE launch.
// ---------------------------------------------------------------------------
__global__ __launch_bounds__(256, 2) void conv_off_fused(
    const unsigned short* __restrict__ A,    // A1k [768][1728]
    const unsigned short* __restrict__ xt,   // [N][P][64] bf16
    const float* __restrict__ bias,          // [648]
    unsigned short* __restrict__ off2)       // [N][216*P][3] bf16
{
    __shared__ __align__(16) short SH[35840];
    int tid = threadIdx.x;
    int w = tid >> 6, lane = tid & 63;
    int lm = lane & 15, lq = lane >> 4;

    if (blockIdx.x < 2*490) {
        short* As0 = SH;
        short* Bs  = SH + 2*16*512;
        int n   = blockIdx.x / 490;
        int bid = blockIdx.x % 490;
        int mt = bid / 98, nt = bid % 98;
        int m0 = mt*128, p0 = nt*256;

        const unsigned short* xtn = xt + (size_t)n*P_*C_;
        unsigned short* out2 = off2 + (size_t)n*216*P_*3;

        const char* Ab0 = (const char*)A + (size_t)(m0 + w*32 + lm)*KB_ + lq*16;
        const char* Ab1 = Ab0 + (size_t)16*KB_;

        int oct = lane & 7;
        int prj[8], dj[8], hj[8], wj[8];
        #pragma unroll
        for (int j = 0; j < 8; ++j) {
            int prow = j*32 + w*8 + (lane >> 3);
            prj[j] = prow;
            int p = p0 + prow;
            dj[j] = p / HW_;
            int hw2 = p % HW_;
            hj[j] = hw2 / W_;
            wj[j] = hw2 % W_;
        }

        auto stageA = [&](int kt, int buf) {
            __builtin_amdgcn_global_load_lds((const AS1 unsigned*)(Ab0 + kt*128),      (AS3 unsigned*)(As0 + buf*8192 + (w*2)*512),     16, 0, 0);
            __builtin_amdgcn_global_load_lds((const AS1 unsigned*)(Ab1 + kt*128),      (AS3 unsigned*)(As0 + buf*8192 + (w*2+1)*512),   16, 0, 0);
            __builtin_amdgcn_global_load_lds((const AS1 unsigned*)(Ab0 + kt*128 + 64), (AS3 unsigned*)(As0 + buf*8192 + (8+w*2)*512),   16, 0, 0);
            __builtin_amdgcn_global_load_lds((const AS1 unsigned*)(Ab1 + kt*128 + 64), (AS3 unsigned*)(As0 + buf*8192 + (8+w*2+1)*512), 16, 0, 0);
        };
        auto loadB = [&](int kt, uint4* B) {
            int kd = kt/9 - 1, kh = (kt/3)%3 - 1, kw = kt%3 - 1;
            int delta = kd*HW_ + kh*W_ + kw;
            #pragma unroll
            for (int j = 0; j < 8; ++j) {
                bool v = ((unsigned)(dj[j]+kd) < (unsigned)D_) &&
                         ((unsigned)(hj[j]+kh) < (unsigned)H_) &&
                         ((unsigned)(wj[j]+kw) < (unsigned)W_);
                uint4 val = {0u,0u,0u,0u};
                if (v) val = *(const uint4*)(xtn + (size_t)(p0 + prj[j] + delta)*C_ + oct*8);
                B[j] = val;
            }
        };

        int mh = w >> 1, nh = w & 1;
        floatx4 acc[4][8];
        #pragma unroll
        for (int i = 0; i < 4; ++i)
            #pragma unroll
            for (int j = 0; j < 8; ++j)
                acc[i][j] = (floatx4){0.f, 0.f, 0.f, 0.f};

        uint4 Bcur[8], Bnext[8];
        #pragma unroll
        for (int j = 0; j < 8; ++j) Bnext[j] = (uint4){0u,0u,0u,0u};
        stageA(0, 0);
        loadB(0, Bcur);

        for (int kt = 0; kt < 27; ++kt) {
            int buf = kt & 1;
            __syncthreads();
            #pragma unroll
            for (int j = 0; j < 8; ++j) {
                int chunk = (oct>>2)*16 + (prj[j]>>4);
                *(uint4*)&Bs[chunk*512 + ((oct&3)*16 + ((prj[j]&15) ^ oct))*8] = Bcur[j];
            }
            __syncthreads();
            if (kt < 26) { stageA(kt+1, buf^1); loadB(kt+1, Bnext); }
            #pragma unroll
            for (int ks = 0; ks < 2; ++ks) {
                int swzB = (lq*16 + (lm ^ (ks*4 + lq)))*8;
                shortx8 a[4];
                #pragma unroll
                for (int i = 0; i < 4; ++i) a[i] = *(const shortx8*)&As0[buf*8192 + (ks*8 + 4*mh + i)*512 + lane*8];
                #pragma unroll
                for (int j = 0; j < 8; ++j) {
                    shortx8 b = *(const shortx8*)&Bs[(ks*16 + 8*nh + j)*512 + swzB];
                    #pragma unroll
                    for (int i = 0; i < 4; ++i)
                        acc[i][j] = __builtin_amdgcn_mfma_f32_16x16x32_bf16(a[i], b, acc[i][j], 0, 0, 0);
                }
            }
            #pragma unroll
            for (int j = 0; j < 8; ++j) Bcur[j] = Bnext[j];
        }

        #pragma unroll
        for (int i = 0; i < 4; ++i) {
            int cob = m0 + (4*mh+i)*16 + lq*4;
            #pragma unroll
            for (int r = 0; r < 4; ++r) {
                int co = cob + r;    // < 640 always (mt <= 4)
                float bv = bias[co];
                int row2 = co / 3, comp = co % 3;
                size_t base = (size_t)row2*P_*3 + comp;
                #pragma unroll
                for (int j = 0; j < 8; ++j) {
                    int col = p0 + (8*nh+j)*16 + lm;
                    out2[base + (size_t)col*3] = f2b(acc[i][j][r] + bv);
                }
            }
        }
    } else {
        short* As = SH;
        short* Bs = SH + 54*512;
        int t  = blockIdx.x - 2*490;
        int n  = t / 196;
        int p0 = (t % 196)*128;

        const unsigned short* xtn = xt + (size_t)n*P_*C_;
        unsigned short* out2 = off2 + (size_t)n*216*P_*3;

        const char* Abase = (const char*)A + (size_t)(640 + lm)*KB_ + lq*16;
        for (int ch = w; ch < 54; ch += 4)
            __builtin_amdgcn_global_load_lds((const AS1 unsigned*)(Abase + ch*64),
                                             (AS3 unsigned*)(As + ch*512), 16, 0, 0);

        int oct = lane & 7;
        int prj[4], dj[4], hj[4], wj[4];
        #pragma unroll
        for (int j = 0; j < 4; ++j) {
            int prow = j*32 + w*8 + (lane >> 3);
            prj[j] = prow;
            int p = p0 + prow;
            dj[j] = p / HW_;
            int hw2 = p % HW_;
            hj[j] = hw2 / W_;
            wj[j] = hw2 % W_;
        }
        auto loadB = [&](int kt, uint4* B) {
            int kd = kt/9 - 1, kh = (kt/3)%3 - 1, kw = kt%3 - 1;
            int delta = kd*HW_ + kh*W_ + kw;
            #pragma unroll
            for (int j = 0; j < 4; ++j) {
                bool v = ((unsigned)(dj[j]+kd) < (unsigned)D_) &&
                         ((unsigned)(hj[j]+kh) < (unsigned)H_) &&
                         ((unsigned)(wj[j]+kw) < (unsigned)W_);
                uint4 val = {0u,0u,0u,0u};
                if (v) val = *(const uint4*)(xtn + (size_t)(p0 + prj[j] + delta)*C_ + oct*8);
                B[j] = val;
            }
        };

        floatx4 acc[2];
        acc[0] = (floatx4){0.f,0.f,0.f,0.f};
        acc[1] = (floatx4){0.f,0.f,0.f,0.f};

        uint4 Bcur[4], Bnext[4];
        #pragma unroll
        for (int j = 0; j < 4; ++j) Bnext[j] = (uint4){0u,0u,0u,0u};
        loadB(0, Bcur);

        for (int kt = 0; kt < 27; ++kt) {
            __syncthreads();
            #pragma unroll
            for (int j = 0; j < 4; ++j) {
                int chunk = (oct>>2)*8 + (prj[j]>>4);
                *(uint4*)&Bs[chunk*512 + ((oct&3)*16 + ((prj[j]&15) ^ oct))*8] = Bcur[j];
            }
            __syncthreads();
            if (kt < 26) loadB(kt+1, Bnext);
            #pragma unroll
            for (int ks = 0; ks < 2; ++ks) {
                int swzB = (lq*16 + (lm ^ (ks*4 + lq)))*8;
                shortx8 a = *(const shortx8*)&As[(kt*2 + ks)*512 + lane*8];
                #pragma unroll
                for (int j = 0; j < 2; ++j) {
                    shortx8 b = *(const shortx8*)&Bs[(ks*8 + w*2 + j)*512 + swzB];
                    acc[j] = __builtin_amdgcn_mfma_f32_16x16x32_bf16(a, b, acc[j], 0, 0, 0);
                }
            }
            #pragma unroll
            for (int j = 0; j < 4; ++j) Bcur[j] = Bnext[j];
        }

        #pragma unroll
        for (int j = 0; j < 2; ++j) {
            #pragma unroll
            for (int r = 0; r < 4; ++r) {
                int co = 640 + lq*4 + r;
                if (co < CO_OFF_) {
                    int col = p0 + w*32 + j*16 + lm;
                    out2[((size_t)(co/3)*P_ + col)*3 + (co%3)] = f2b(acc[j][r] + bias[co]);
                }
            }
        }
    }
}

// ---------------------------------------------------------------------------
// deform fused v11: 64-p tiles — each thread owns TWO interps (p, p+32).
// Same v6 single-barrier structure; the fixed per-iteration gather stall
// (~200cy, reduce waiting on its own gathers) is amortized over 2x work,
// and per-thread memory ILP doubles (R6's proven amortization lever).
// BN1 partials fused in epilogue. LDS 32KB: A dbuf 2x8KB, B dbuf 2x8KB.
// ---------------------------------------------------------------------------
__global__ __launch_bounds__(256) void deform_fused(
    const unsigned short* __restrict__ xt,   // [N][P][64] bf16
    const unsigned short* __restrict__ off2, // [N][216*P][3] bf16
    const unsigned short* __restrict__ A,    // A1t [64][1728]
    unsigned short* __restrict__ y1t,        // [N][P][64] bf16
    float* __restrict__ bn1p)                // [784][128] block partials
{
    __shared__ __align__(16) short SH[16384]; // A dbuf [0,8192) B dbuf [8192,16384)
    int tid = threadIdx.x;
    int w = tid >> 6, lane = tid & 63;
    int n  = blockIdx.x / (P_/64);
    int p0 = (blockIdx.x % (P_/64))*64;
    int lm = lane & 15, lq = lane >> 4;
    int mh = w >> 1, nh = w & 1;

    const unsigned short* offn = off2 + (size_t)n*216*P_*3;
    const uint4* xg0 = (const uint4*)(xt + (size_t)n*P_*C_);
    const char* Ab = (const char*)A + (size_t)(w*16 + lm)*KB_ + lq*16;

    int g = lane & 7;
    int prow = tid >> 3;          // 0..31; j=0 -> p0+prow, j=1 -> p0+32+prow
    int dd[2], hh[2], ww[2];
    #pragma unroll
    for (int j = 0; j < 2; ++j) {
        int p = p0 + j*32 + prow;
        dd[j] = p / HW_;
        int hw2 = p % HW_;
        hh[j] = hw2 / W_;
        ww[j] = hw2 % W_;
    }
    int bch0  = (g>>2)*4 + (prow>>4);          // j adds 2
    int boffs = ((g&3)*16 + ((prow&15) ^ g))*8;

    const unsigned short* offp = offn + ((size_t)(g*K_)*P_ + p0 + prow)*3;

    auto stageA = [&](int kt, int buf) {
        __builtin_amdgcn_global_load_lds((const AS1 unsigned*)(Ab + kt*128),      (AS3 unsigned*)(SH + buf*4096 + w*512),     16, 0, 0);
        __builtin_amdgcn_global_load_lds((const AS1 unsigned*)(Ab + kt*128 + 64), (AS3 unsigned*)(SH + buf*4096 + (4+w)*512), 16, 0, 0);
    };
    auto loadOff = [&](int kt, float (*o)[3]) {
        const unsigned short* q = offp + (unsigned)(kt*(P_*3));
        o[0][0] = b2f(q[0]);  o[0][1] = b2f(q[1]);  o[0][2] = b2f(q[2]);
        o[1][0] = b2f(q[96]); o[1][1] = b2f(q[97]); o[1][2] = b2f(q[98]);   // p+32
    };
    auto issueCornersJ = [&](int kt, const float* o, int j, uint4* V, float* Wt) {
        int kd = kt/9 - 1, kh = (kt/3)%3 - 1, kw = kt%3 - 1;
        float pd = (float)(dd[j] + kd) + o[0];
        float ph = (float)(hh[j] + kh) + o[1];
        float pw = (float)(ww[j] + kw) + o[2];
        float fd0 = floorf(pd), fh0 = floorf(ph), fw0 = floorf(pw);
        int d0 = (int)fd0, h0 = (int)fh0, w0i = (int)fw0;
        float fd = pd - fd0, fh = ph - fh0, fw = pw - fw0;
        int dc0 = min(max(d0, 0), D_-1),   dc1 = min(max(d0+1, 0), D_-1);
        int hc0 = min(max(h0, 0), H_-1),   hc1 = min(max(h0+1, 0), H_-1);
        int wc0 = min(max(w0i, 0), W_-1),  wc1 = min(max(w0i+1, 0), W_-1);
        float wd0 = ((unsigned)d0      < (unsigned)D_) ? 1.f - fd : 0.f;
        float wd1 = ((unsigned)(d0+1)  < (unsigned)D_) ? fd       : 0.f;
        float wh0 = ((unsigned)h0      < (unsigned)H_) ? 1.f - fh : 0.f;
        float wh1 = ((unsigned)(h0+1)  < (unsigned)H_) ? fh       : 0.f;
        float ww0 = ((unsigned)w0i     < (unsigned)W_) ? 1.f - fw : 0.f;
        float ww1 = ((unsigned)(w0i+1) < (unsigned)W_) ? fw       : 0.f;
        int rb00 = (dc0*H_ + hc0)*W_, rb01 = (dc0*H_ + hc1)*W_;
        int rb10 = (dc1*H_ + hc0)*W_, rb11 = (dc1*H_ + hc1)*W_;
        float wdh00 = wd0*wh0, wdh01 = wd0*wh1, wdh10 = wd1*wh0, wdh11 = wd1*wh1;
        V[0] = xg0[(size_t)(rb00+wc0)*8 + g];  Wt[0] = wdh00*ww0;
        V[1] = xg0[(size_t)(rb00+wc1)*8 + g];  Wt[1] = wdh00*ww1;
        V[2] = xg0[(size_t)(rb01+wc0)*8 + g];  Wt[2] = wdh01*ww0;
        V[3] = xg0[(size_t)(rb01+wc1)*8 + g];  Wt[3] = wdh01*ww1;
        V[4] = xg0[(size_t)(rb10+wc0)*8 + g];  Wt[4] = wdh10*ww0;
        V[5] = xg0[(size_t)(rb10+wc1)*8 + g];  Wt[5] = wdh10*ww1;
        V[6] = xg0[(size_t)(rb11+wc0)*8 + g];  Wt[6] = wdh11*ww0;
        V[7] = xg0[(size_t)(rb11+wc1)*8 + g];  Wt[7] = wdh11*ww1;
    };
    auto reduceCorners = [&](const uint4* V, const float* Wt, uint4& o4) {
        float res[CPG_];
        #pragma unroll
        for (int c = 0; c < CPG_; ++c) res[c] = 0.f;
        #pragma unroll
        for (int c = 0; c < 8; ++c) {
            uint4 v4 = V[c];
            float wgt = Wt[c];
            res[0] = fmaf(wgt, lof(v4.x), res[0]);
            res[1] = fmaf(wgt, hif(v4.x), res[1]);
            res[2] = fmaf(wgt, lof(v4.y), res[2]);
            res[3] = fmaf(wgt, hif(v4.y), res[3]);
            res[4] = fmaf(wgt, lof(v4.z), res[4]);
            res[5] = fmaf(wgt, hif(v4.z), res[5]);
            res[6] = fmaf(wgt, lof(v4.w), res[6]);
            res[7] = fmaf(wgt, hif(v4.w), res[7]);
        }
        o4.x = cvt_pk_bf16(res[0], res[1]);
        o4.y = cvt_pk_bf16(res[2], res[3]);
        o4.z = cvt_pk_bf16(res[4], res[5]);
        o4.w = cvt_pk_bf16(res[6], res[7]);
    };

    floatx4 acc[2][2];   // [i(o-frag)][j2(p-frag)]
    #pragma unroll
    for (int i = 0; i < 2; ++i)
        #pragma unroll
        for (int j = 0; j < 2; ++j)
            acc[i][j] = (floatx4){0.f,0.f,0.f,0.f};

    float offA[2][3], offB[2][3], offT[2][3];
    uint4 VA[2][8]; float WA[2][8];
    uint4 o4cur;

    stageA(0, 0);
    loadOff(0, offA);
    loadOff(1, offB);
    issueCornersJ(0, offA[0], 0, VA[0], WA[0]);
    issueCornersJ(0, offA[1], 1, VA[1], WA[1]);
    reduceCorners(VA[0], WA[0], o4cur);
    *(uint4*)&SH[8192 + bch0*512 + boffs] = o4cur;
    reduceCorners(VA[1], WA[1], o4cur);
    *(uint4*)&SH[8192 + (bch0+2)*512 + boffs] = o4cur;

    for (int kt = 0; kt < 27; ++kt) {
        int buf = kt & 1;
        __syncthreads();   // Bs[buf] writes + As[buf] staging drained
        if (kt < 26) {
            stageA(kt+1, buf^1);
            if (kt < 25) loadOff(kt+2, offT);
            issueCornersJ(kt+1, offB[0], 0, VA[0], WA[0]);
            issueCornersJ(kt+1, offB[1], 1, VA[1], WA[1]);
        }
        #pragma unroll
        for (int ks = 0; ks < 2; ++ks) {
            int swzB = (lq*16 + (lm ^ (ks*4 + lq)))*8;
            #pragma unroll
            for (int j2 = 0; j2 < 2; ++j2) {
                shortx8 b = *(const shortx8*)&SH[8192 + buf*4096 + (ks*4 + nh*2 + j2)*512 + swzB];
                #pragma unroll
                for (int i = 0; i < 2; ++i) {
                    shortx8 a = *(const shortx8*)&SH[buf*4096 + (ks*4 + 2*mh+i)*512 + lane*8];
                    acc[i][j2] = __builtin_amdgcn_mfma_f32_16x16x32_bf16(a, b, acc[i][j2], 0, 0, 0);
                }
            }
        }
        if (kt < 26) {
            reduceCorners(VA[0], WA[0], o4cur);
            *(uint4*)&SH[8192 + (buf^1)*4096 + bch0*512 + boffs] = o4cur;
            reduceCorners(VA[1], WA[1], o4cur);
            *(uint4*)&SH[8192 + (buf^1)*4096 + (bch0+2)*512 + boffs] = o4cur;
            #pragma unroll
            for (int j = 0; j < 2; ++j) {
                offB[j][0] = offT[j][0]; offB[j][1] = offT[j][1]; offB[j][2] = offT[j][2];
            }
        }
    }

    // epilogue: transpose 64o x 64p tile to y1t[p][o] via LDS (stride 72)
    __syncthreads();
    #pragma unroll
    for (int i = 0; i < 2; ++i) {
        #pragma unroll
        for (int j2 = 0; j2 < 2; ++j2) {
            int ob = mh*32 + i*16 + lq*4;
            int pc = nh*32 + j2*16 + lm;
            #pragma unroll
            for (int rr = 0; rr < 4; ++rr)
                SH[pc*72 + ob + rr] = (short)f2b(acc[i][j2][rr]);
        }
    }
    __syncthreads();
    #pragma unroll
    for (int it = 0; it < 2; ++it) {
        int wi = it*256 + tid;
        int row = wi >> 3, seg = wi & 7;
        uint4 v = *(const uint4*)&SH[row*72 + seg*8];
        *(uint4*)(y1t + ((size_t)n*P_ + p0 + row)*C_ + seg*8) = v;
    }
    // BN1 partials from the y1 tile in LDS (rows 0..63, stride 72)
    {
        float* FS = (float*)(SH + 10240);   // 256 floats
        float* FQ = FS + 256;               // 256 floats (shorts 10240..11264)
        int o = tid & 63, qt = tid >> 6;
        float s = 0.f, q = 0.f;
        #pragma unroll
        for (int pp = 0; pp < 16; ++pp) {
            float v = b2f((unsigned short)SH[(qt*16 + pp)*72 + o]);
            s += v;
            q = fmaf(v, v, q);
        }
        FS[qt*64 + o] = s;
        FQ[qt*64 + o] = q;
        __syncthreads();
        if (tid < 64) {
            float S = FS[tid] + FS[64+tid] + FS[128+tid] + FS[192+tid];
            float Q = FQ[tid] + FQ[64+tid] + FQ[128+tid] + FQ[192+tid];
            bn1p[(size_t)blockIdx.x*128 + tid]      = S;
            bn1p[(size_t)blockIdx.x*128 + 64 + tid] = Q;
        }
    }
}

// ---------------------------------------------------------------------------
// conv2 fused v5 (R9): 64o x 128p blocks, quad-buffer As, BN2 partials.
// ---------------------------------------------------------------------------
__global__ __launch_bounds__(256) void conv2_fused(
    const unsigned short* __restrict__ y1t,  // [N][P][64] bf16
    const float* __restrict__ st1,           // [64] scale, [64] shift
    const unsigned short* __restrict__ A,    // A2t [64][1728]
    const float* __restrict__ bias,          // [64]
    unsigned short* __restrict__ y2,         // [N][64][P] bf16
    float* __restrict__ part2)               // [392][128] block partials
{
    __shared__ __align__(16) short As[4][4096];   // 32 KB quad-buffer
    __shared__ float sc[64], sf[64];
    __shared__ float SP[4][64], SQ[4][64];
    int tid = threadIdx.x;
    if (tid < 64) sc[tid] = st1[tid];
    else if (tid < 128) sf[tid-64] = st1[tid];
    int w = tid >> 6, lane = tid & 63;
    int n  = blockIdx.x / (P_/128);
    int p0 = (blockIdx.x % (P_/128))*128;
    int lm = lane & 15, lq = lane >> 4;

    const unsigned short* y1n = y1t + (size_t)n*P_*C_;
    unsigned short* y2n = y2 + (size_t)n*C_*P_;
    const char* Ab = (const char*)A + (size_t)(w*16 + lm)*KB_ + lq*16;

    int pj[2], dd[2], hh[2], ww[2];
    #pragma unroll
    for (int j = 0; j < 2; ++j) {
        pj[j] = p0 + j*64 + w*16 + lm;
        dd[j] = pj[j] / HW_;
        int hw2 = pj[j] % HW_;
        hh[j] = hw2 / W_;
        ww[j] = hw2 % W_;
    }

    auto stageA = [&](int kt) {
        int buf = kt & 3;
        __builtin_amdgcn_global_load_lds((const AS1 unsigned*)(Ab + kt*128),      (AS3 unsigned*)(&As[buf][w*512]),     16, 0, 0);
        __builtin_amdgcn_global_load_lds((const AS1 unsigned*)(Ab + kt*128 + 64), (AS3 unsigned*)(&As[buf][(4+w)*512]), 16, 0, 0);
    };
    auto issueV = [&](int kt, uint4 (*V)[2], int* M) {
        int kd = kt/9 - 1, kh = (kt/3)%3 - 1, kw = kt%3 - 1;
        int delta = kd*HW_ + kh*W_ + kw;
        #pragma unroll
        for (int j = 0; j < 2; ++j) {
            bool v = ((unsigned)(dd[j]+kd) < (unsigned)D_) &&
                     ((unsigned)(hh[j]+kh) < (unsigned)H_) &&
                     ((unsigned)(ww[j]+kw) < (unsigned)W_);
            M[j] = v ? 1 : 0;
            #pragma unroll
            for (int ks = 0; ks < 2; ++ks) {
                uint4 val = {0u,0u,0u,0u};
                if (v) val = *(const uint4*)(y1n + (size_t)(pj[j] + delta)*C_ + (ks*4 + lq)*8);
                V[j][ks] = val;
            }
        }
    };
    auto reduceT = [&](uint4 V, int ks, int M) -> shortx8 {
        uint4 o4 = {0u,0u,0u,0u};
        if (M) {
            int cb = (ks*4 + lq)*8;
            float r0 = fmaxf(lof(V.x)*sc[cb+0] + sf[cb+0], 0.f);
            float r1 = fmaxf(hif(V.x)*sc[cb+1] + sf[cb+1], 0.f);
            float r2 = fmaxf(lof(V.y)*sc[cb+2] + sf[cb+2], 0.f);
            float r3 = fmaxf(hif(V.y)*sc[cb+3] + sf[cb+3], 0.f);
            float r4 = fmaxf(lof(V.z)*sc[cb+4] + sf[cb+4], 0.f);
            float r5 = fmaxf(hif(V.z)*sc[cb+5] + sf[cb+5], 0.f);
            float r6 = fmaxf(lof(V.w)*sc[cb+6] + sf[cb+6], 0.f);
            float r7 = fmaxf(hif(V.w)*sc[cb+7] + sf[cb+7], 0.f);
            o4.x = cvt_pk_bf16(r0, r1);
            o4.y = cvt_pk_bf16(r2, r3);
            o4.z = cvt_pk_bf16(r4, r5);
            o4.w = cvt_pk_bf16(r6, r7);
        }
        return *(shortx8*)&o4;
    };

    floatx4 acc[4][2];
    #pragma unroll
    for (int i = 0; i < 4; ++i)
        #pragma unroll
        for (int j = 0; j < 2; ++j)
            acc[i][j] = (floatx4){0.f,0.f,0.f,0.f};

    auto mfmaTap = [&](int kt, uint4 (*V)[2], const int* M) {
        int buf = kt & 3;
        #pragma unroll
        for (int j = 0; j < 2; ++j) {
            shortx8 b0 = reduceT(V[j][0], 0, M[j]);
            shortx8 b1 = reduceT(V[j][1], 1, M[j]);
            #pragma unroll
            for (int i = 0; i < 4; ++i) {
                shortx8 a = *(const shortx8*)&As[buf][(0*4 + i)*512 + lane*8];
                acc[i][j] = __builtin_amdgcn_mfma_f32_16x16x32_bf16(a, b0, acc[i][j], 0, 0, 0);
            }
            #pragma unroll
            for (int i = 0; i < 4; ++i) {
                shortx8 a = *(const shortx8*)&As[buf][(1*4 + i)*512 + lane*8];
                acc[i][j] = __builtin_amdgcn_mfma_f32_16x16x32_bf16(a, b1, acc[i][j], 0, 0, 0);
            }
        }
    };

    uint4 VA[2][2], VB[2][2];
    int MA[2], MB[2];
    stageA(0); stageA(1);
    issueV(0, VA, MA);
    issueV(1, VB, MB);

    for (int kt = 0; kt < 26; kt += 2) {
        __syncthreads();
        stageA(kt+2);
        if (kt+3 <= 26) stageA(kt+3);
        {
            uint4 Vc[2][2];
            #pragma unroll
            for (int j = 0; j < 2; ++j) { Vc[j][0] = VA[j][0]; Vc[j][1] = VA[j][1]; }
            int Mc[2] = {MA[0], MA[1]};
            issueV(kt+2, VA, MA);
            mfmaTap(kt, Vc, Mc);
        }
        {
            uint4 Vc[2][2];
            #pragma unroll
            for (int j = 0; j < 2; ++j) { Vc[j][0] = VB[j][0]; Vc[j][1] = VB[j][1]; }
            int Mc[2] = {MB[0], MB[1]};
            if (kt+3 <= 26) issueV(kt+3, VB, MB);
            mfmaTap(kt+1, Vc, Mc);
        }
    }
    __syncthreads();
    mfmaTap(26, VA, MA);

    // epilogue: y2 write + BN2 partials (128 p per block)
    #pragma unroll
    for (int i = 0; i < 4; ++i) {
        #pragma unroll
        for (int r = 0; r < 4; ++r) {
            int co = i*16 + lq*4 + r;
            float v0 = acc[i][0][r] + bias[co];
            float v1 = acc[i][1][r] + bias[co];
            y2n[(size_t)co*P_ + pj[0]] = f2b(v0);
            y2n[(size_t)co*P_ + pj[1]] = f2b(v1);
            float s = v0 + v1;
            float q = v0*v0 + v1*v1;
            #pragma unroll
            for (int m = 1; m < 16; m <<= 1) {
                s += __shfl_xor(s, m);
                q += __shfl_xor(q, m);
            }
            if (lm == 0) { SP[w][co] = s; SQ[w][co] = q; }
        }
    }
    __syncthreads();
    if (tid < 64) {
        float S = SP[0][tid] + SP[1][tid] + SP[2][tid] + SP[3][tid];
        float Q = SQ[0][tid] + SQ[1][tid] + SQ[2][tid] + SQ[3][tid];
        part2[(size_t)blockIdx.x*128 + tid]      = S;
        part2[(size_t)blockIdx.x*128 + 64 + tid] = Q;
    }
}

// ---------------------------------------------------------------------------
// BN1 finalize from deform partials (784 blocks) -> st1 (scale, shift)
// ---------------------------------------------------------------------------
__global__ __launch_bounds__(256) void stats_final_kernel(
    const float* __restrict__ part,
    const float* __restrict__ gamma, const float* __restrict__ beta,
    float* __restrict__ st1)
{
    int tid = threadIdx.x;
    int c = tid & 63, seg = tid >> 6;
    float S = 0.f, Q = 0.f;
    for (int b = seg*196; b < seg*196 + 196; ++b) {
        S += part[(size_t)b*128 + c];
        Q += part[(size_t)b*128 + 64 + c];
    }
    __shared__ float ss[256], qq[256];
    ss[tid] = S; qq[tid] = Q;
    __syncthreads();
    if (tid < 64) {
        float St = ss[tid] + ss[64+tid] + ss[128+tid] + ss[192+tid];
        float Qt = qq[tid] + qq[64+tid] + qq[128+tid] + qq[192+tid];
        const float inv = 1.f / (float)(N_*P_);
        float m = St * inv;
        float var = Qt * inv - m*m;
        float scale = rsqrtf(var + 1e-5f) * gamma[tid];
        st1[tid]      = scale;
        st1[64 + tid] = beta[tid] - m*scale;
    }
}

// ---------------------------------------------------------------------------
// BN2 finalize from conv2 partials (392 blocks) -> st2 (scale, shift)
// ---------------------------------------------------------------------------
__global__ __launch_bounds__(256) void bn2_final_kernel(
    const float* __restrict__ part2,
    const float* __restrict__ gamma, const float* __restrict__ beta,
    float* __restrict__ st2)
{
    int tid = threadIdx.x;
    int c = tid & 63, seg = tid >> 6;
    float S = 0.f, Q = 0.f;
    for (int b = seg*98; b < seg*98 + 98; ++b) {
        S += part2[(size_t)b*128 + c];
        Q += part2[(size_t)b*128 + 64 + c];
    }
    __shared__ float ss[256], qq[256];
    ss[tid] = S; qq[tid] = Q;
    __syncthreads();
    if (tid < 64) {
        float St = ss[tid] + ss[64+tid] + ss[128+tid] + ss[192+tid];
        float Qt = qq[tid] + qq[64+tid] + qq[128+tid] + qq[192+tid];
        const float inv = 1.f / (float)(N_*P_);
        float m = St * inv;
        float var = Qt * inv - m*m;
        float scale = rsqrtf(var + 1e-5f) * gamma[tid];
        st2[tid]      = scale;
        st2[64 + tid] = beta[tid] - m*scale;
    }
}

// ---------------------------------------------------------------------------
// BN2 apply + residual + ReLU, vectorized x4 (uint2 y2 / float4 x,out)
// ---------------------------------------------------------------------------
__global__ __launch_bounds__(256) void bn_add_relu_kernel(
    const unsigned short* __restrict__ y2, const float* __restrict__ x,
    const float* __restrict__ st2, float* __restrict__ out)
{
    size_t i4 = ((size_t)blockIdx.x*256 + threadIdx.x)*4;
    int c = (int)((i4 / P_) % C_);
    float scale = st2[c], shift = st2[64 + c];
    uint2 yv = *(const uint2*)(y2 + i4);
    float4 xv = *(const float4*)(x + i4);
    float4 o;
    o.x = fmaxf(fmaf(lof(yv.x), scale, shift) + xv.x, 0.f);
    o.y = fmaxf(fmaf(hif(yv.x), scale, shift) + xv.y, 0.f);
    o.z = fmaxf(fmaf(lof(yv.y), scale, shift) + xv.z, 0.f);
    o.w = fmaxf(fmaf(hif(yv.y), scale, shift) + xv.w, 0.f);
    *(float4*)(out + i4) = o;
}

// ---------------------------------------------------------------------------
extern "C" void kernel_launch(void* const* d_in, const int* in_sizes, int n_in,
                              void* d_out, int out_size, void* d_ws, size_t ws_size,
                              hipStream_t stream) {
    const float* x     = (const float*)d_in[0];
    const float* w_off = (const float*)d_in[1];
    const float* b_off = (const float*)d_in[2];
    const float* w1    = (const float*)d_in[3];
    const float* g1    = (const float*)d_in[4];
    const float* be1   = (const float*)d_in[5];
    const float* w2    = (const float*)d_in[6];
    const float* b2    = (const float*)d_in[7];
    const float* g2    = (const float*)d_in[8];
    const float* be2   = (const float*)d_in[9];
    float* out = (float*)d_out;

    // workspace (~89 MB)
    float* st1  = (float*)d_ws;                              // 128 (scale/shift BN1)
    float* st2  = st1 + 128;                                 // 128 (scale/shift BN2)
    float* bn1p = st2 + 128;                                 // up to 1568*128 alloc (784*128 used)
    unsigned short* off2 = (unsigned short*)(bn1p + 1568*128); // N*216*P*3 bf16 (65 MB)
    unsigned short* xt  = off2 + (size_t)N_*216*P_*3;        // N*P*64 bf16 (6.4 MB)
    unsigned short* y1t = xt  + (size_t)N_*P_*C_;            // N*P*64 bf16 (6.4 MB)
    unsigned short* y2  = y1t + (size_t)N_*P_*C_;            // N*64*P bf16 (6.4 MB)
    unsigned short* A1k = y2  + (size_t)N_*C_*P_;            // 768*1728 bf16 (2.65 MB)
    unsigned short* A1t = A1k + (size_t)MP_*KK_;             // 64*1728 bf16
    unsigned short* A2t = A1t + (size_t)C_*KK_;              // 64*1728 bf16
    // part2 [392][128] reuses off2's space (off2 dead after deform_fused)
    float* part2 = (float*)off2;

    // prep: transpose + all weight permutes in ONE launch
    prep_kernel<<<784 + 5184 + 432 + 432, 256, 0, stream>>>(
        x, xt, w_off, A1k, w1, A1t, w2, A2t);

    // conv_off fused -> off2 (both n): main 128x256 tiles + tail MERGED
    conv_off_fused<<<2*490 + 2*196, 256, 0, stream>>>(A1k, xt, b_off, off2);

    // deform fused -> y1t + BN1 partials (both n), 64-p tiles
    deform_fused<<<N_*(P_/64), 256, 0, stream>>>(xt, off2, A1t, y1t, bn1p);

    // BN1 finalize
    stats_final_kernel<<<1, 256, 0, stream>>>(bn1p, g1, be1, st1);

    // conv2 fused (BN1+ReLU on read) -> y2 + BN2 partials, 128p blocks
    conv2_fused<<<N_*(P_/128), 256, 0, stream>>>(y1t, st1, A2t, b2, y2, part2);

    // BN2 finalize + apply + residual + ReLU -> out (fp32)
    bn2_final_kernel<<<1, 256, 0, stream>>>(part2, g2, be2, st2);
    bn_add_relu_kernel<<<(N_*C_*P_)/1024, 256, 0, stream>>>(y2, x, st2, out);
}